// Round 6
// baseline (1923.609 us; speedup 1.0000x reference)
//
#include <hip/hip_runtime.h>

#define NN 50000
#define NE 1200000
#define DIM 64
#define NB 782            // node buckets of 64 nodes: ceil(50000/64)
#define SLICES 256
#define ES 4688           // ceil(NE/SLICES)

// ---------------- coarse histograms per (slice, bucket) — LDS only, no global atomics
__global__ __launch_bounds__(256) void k_bhist(const int* __restrict__ ei,
                                               int* __restrict__ part_u,
                                               int* __restrict__ part_v) {
    __shared__ int hu[NB], hv[NB];
    int t = threadIdx.x, s = blockIdx.x;
    for (int i = t; i < NB; i += 256) { hu[i] = 0; hv[i] = 0; }
    __syncthreads();
    int e0 = s * ES, e1 = min(e0 + ES, NE);
    for (int e = e0 + t; e < e1; e += 256) {
        atomicAdd(&hu[ei[e] >> 6], 1);        // LDS atomic
        atomicAdd(&hv[ei[NE + e] >> 6], 1);   // LDS atomic
    }
    __syncthreads();
    for (int i = t; i < NB; i += 256) {
        part_u[s * NB + i] = hu[i];
        part_v[s * NB + i] = hv[i];
    }
}

// ---------------- column totals: tot[c] = sum_s part[s][c]  (c<NB: u, else v)
__global__ __launch_bounds__(256) void k_scanA(const int* __restrict__ part_u,
                                               const int* __restrict__ part_v,
                                               int* __restrict__ tot) {
    int w = threadIdx.x >> 6, l = threadIdx.x & 63;
    int c = blockIdx.x * 4 + w;
    if (c >= 2 * NB) return;
    const int* m = (c < NB) ? part_u : part_v;
    int col = (c < NB) ? c : c - NB;
    int sum = 0;
    for (int s = l; s < SLICES; s += 64) sum += m[s * NB + col];
    for (int off = 32; off; off >>= 1) sum += __shfl_down(sum, off, 64);
    if (l == 0) tot[c] = sum;
}

// ---------------- exclusive scan of both NB-vectors -> base_u[NB+1], base_v[NB+1]
__global__ __launch_bounds__(256) void k_scanB(const int* __restrict__ tot,
                                               int* __restrict__ base_u,
                                               int* __restrict__ base_v) {
    __shared__ int sd[256];
    int t = threadIdx.x;
    for (int pass = 0; pass < 2; ++pass) {
        const int* src = tot + pass * NB;
        int* dst = pass ? base_v : base_u;
        int base = t * 4;
        int v0 = (base + 0 < NB) ? src[base + 0] : 0;
        int v1 = (base + 1 < NB) ? src[base + 1] : 0;
        int v2 = (base + 2 < NB) ? src[base + 2] : 0;
        int v3 = (base + 3 < NB) ? src[base + 3] : 0;
        int p1 = v0, p2 = v0 + v1, p3 = p2 + v2, t4 = p3 + v3;
        sd[t] = t4;
        __syncthreads();
        for (int off = 1; off < 256; off <<= 1) {
            int x = 0;
            if (t >= off) x = sd[t - off];
            __syncthreads();
            sd[t] += x;
            __syncthreads();
        }
        int excl = sd[t] - t4;
        if (base + 0 < NB) dst[base + 0] = excl;
        if (base + 1 < NB) dst[base + 1] = excl + p1;
        if (base + 2 < NB) dst[base + 2] = excl + p2;
        if (base + 3 < NB) dst[base + 3] = excl + p3;
        if (t == 255) dst[NB] = sd[255];
        __syncthreads();
    }
}

// ---------------- rebase partials in place: part[s][c] = base[c] + prefix_{s'<s}
__global__ __launch_bounds__(256) void k_scanC(int* __restrict__ part_u,
                                               int* __restrict__ part_v,
                                               const int* __restrict__ base_u,
                                               const int* __restrict__ base_v) {
    int w = threadIdx.x >> 6, l = threadIdx.x & 63;
    int c = blockIdx.x * 4 + w;
    if (c >= 2 * NB) return;
    int* m = (c < NB) ? part_u : part_v;
    const int* bs = (c < NB) ? base_u : base_v;
    int col = (c < NB) ? c : c - NB;
    // lane l owns slices 4l..4l+3 (ascending) — SLICES = 64*4
    int v0 = m[(l * 4 + 0) * NB + col];
    int v1 = m[(l * 4 + 1) * NB + col];
    int v2 = m[(l * 4 + 2) * NB + col];
    int v3 = m[(l * 4 + 3) * NB + col];
    int p1 = v0, p2 = v0 + v1, p3 = p2 + v2, t4 = p3 + v3;
    int inc = t4;
    for (int off = 1; off < 64; off <<= 1) {
        int x = __shfl_up(inc, off, 64);
        if (l >= off) inc += x;
    }
    int excl = inc - t4 + bs[col];
    m[(l * 4 + 0) * NB + col] = excl;
    m[(l * 4 + 1) * NB + col] = excl + p1;
    m[(l * 4 + 2) * NB + col] = excl + p2;
    m[(l * 4 + 3) * NB + col] = excl + p3;
}

// ---------------- scatter u values into u-bucket-sorted order (LDS cursors)
__global__ __launch_bounds__(256) void k_uscat(const int* __restrict__ ei,
                                               const int* __restrict__ part_u,
                                               int* __restrict__ usort) {
    __shared__ int cur[NB];
    int t = threadIdx.x, s = blockIdx.x;
    for (int i = t; i < NB; i += 256) cur[i] = part_u[s * NB + i];
    __syncthreads();
    int e0 = s * ES, e1 = min(e0 + ES, NE);
    for (int e = e0 + t; e < e1; e += 256) {
        int u = ei[e];
        int pos = atomicAdd(&cur[u >> 6], 1);   // LDS atomic
        usort[pos] = u;
    }
}

// ---------------- per-bucket fine count of u -> dis = rsqrt(deg+1)
__global__ __launch_bounds__(256) void k_ucnt(const int* __restrict__ usort,
                                              const int* __restrict__ base_u,
                                              float* __restrict__ dis) {
    __shared__ int sh[4][64];
    int w = threadIdx.x >> 6, l = threadIdx.x & 63;
    int b = blockIdx.x * 4 + w;
    sh[w][l] = 0;
    __syncthreads();
    if (b < NB) {
        int r0 = base_u[b], r1 = base_u[b + 1];
        for (int i = r0 + l; i < r1; i += 64)
            atomicAdd(&sh[w][usort[i] & 63], 1);   // LDS atomic
    }
    __syncthreads();
    if (b < NB) {
        int n = (b << 6) + l;
        if (n < NN) dis[n] = rsqrtf((float)sh[w][l] + 1.0f);
    }
}

// ---------------- scatter edge records into v-bucket-sorted order
// record: x = u | (v&63)<<16, y = norm (full fp32)
__global__ __launch_bounds__(256) void k_vscat(const int* __restrict__ ei,
                                               const float* __restrict__ dis,
                                               const int* __restrict__ part_v,
                                               int2* __restrict__ edges) {
    __shared__ int cur[NB];
    int t = threadIdx.x, s = blockIdx.x;
    for (int i = t; i < NB; i += 256) cur[i] = part_v[s * NB + i];
    __syncthreads();
    int e0 = s * ES, e1 = min(e0 + ES, NE);
    for (int e = e0 + t; e < e1; e += 256) {
        int u = ei[e], v = ei[NE + e];
        float nm = dis[u] * dis[v];
        int pos = atomicAdd(&cur[v >> 6], 1);   // LDS atomic
        edges[pos] = make_int2(u | ((v & 63) << 16), __float_as_int(nm));
    }
}

// ---------------- fp32 GEMM: C[M,64] = A[M,64] @ W[64,64] + bias
// mode 0: plain store; 1: relu+store; 2: relu + column-sum only (no store).
__global__ __launch_bounds__(256) void k_gemm(const float* __restrict__ A,
                                              const float* __restrict__ W,
                                              const float* __restrict__ bias,
                                              float* __restrict__ C,
                                              int M, int mode,
                                              float* __restrict__ colsum) {
    __shared__ float As[64][68];
    __shared__ float Bs[64][64];
    int t = threadIdx.x;
    int row0 = blockIdx.x * 64;
#pragma unroll
    for (int i = 0; i < 4; ++i) {
        int idx = t + i * 256;
        int r = idx >> 4, c = (idx & 15) << 2;
        float4 val = make_float4(0.f, 0.f, 0.f, 0.f);
        if (row0 + r < M) val = *(const float4*)&A[(size_t)(row0 + r) * DIM + c];
        *(float4*)&As[r][c] = val;
        *(float4*)&Bs[r][c] = *(const float4*)&W[r * DIM + c];
    }
    __syncthreads();

    int r0 = (t >> 4) * 4;
    int c0 = (t & 15) * 4;
    float acc[4][4] = {};
#pragma unroll
    for (int k = 0; k < 64; k += 4) {
        float4 b0 = *(float4*)&Bs[k + 0][c0];
        float4 b1 = *(float4*)&Bs[k + 1][c0];
        float4 b2 = *(float4*)&Bs[k + 2][c0];
        float4 b3 = *(float4*)&Bs[k + 3][c0];
#pragma unroll
        for (int i = 0; i < 4; ++i) {
            float4 av = *(float4*)&As[r0 + i][k];
            acc[i][0] = fmaf(av.x, b0.x, fmaf(av.y, b1.x, fmaf(av.z, b2.x, fmaf(av.w, b3.x, acc[i][0]))));
            acc[i][1] = fmaf(av.x, b0.y, fmaf(av.y, b1.y, fmaf(av.z, b2.y, fmaf(av.w, b3.y, acc[i][1]))));
            acc[i][2] = fmaf(av.x, b0.z, fmaf(av.y, b1.z, fmaf(av.z, b2.z, fmaf(av.w, b3.z, acc[i][2]))));
            acc[i][3] = fmaf(av.x, b0.w, fmaf(av.y, b1.w, fmaf(av.z, b2.w, fmaf(av.w, b3.w, acc[i][3]))));
        }
    }

    float4 bv = *(const float4*)&bias[c0];
    float csum[4] = {0.f, 0.f, 0.f, 0.f};
#pragma unroll
    for (int i = 0; i < 4; ++i) {
        int r = row0 + r0 + i;
        if (r < M) {
            float4 o;
            o.x = acc[i][0] + bv.x;
            o.y = acc[i][1] + bv.y;
            o.z = acc[i][2] + bv.z;
            o.w = acc[i][3] + bv.w;
            if (mode != 0) {
                o.x = fmaxf(o.x, 0.f); o.y = fmaxf(o.y, 0.f);
                o.z = fmaxf(o.z, 0.f); o.w = fmaxf(o.w, 0.f);
            }
            if (mode != 2) {
                *(float4*)&C[(size_t)r * DIM + c0] = o;
            } else {
                csum[0] += o.x; csum[1] += o.y; csum[2] += o.z; csum[3] += o.w;
            }
        }
    }
    if (mode == 2) {
        float* red = &As[0][0];
        __syncthreads();
        *(float4*)&red[(t >> 4) * 64 + c0] = make_float4(csum[0], csum[1], csum[2], csum[3]);
        __syncthreads();
        if (t < 64) {
            float s = 0.f;
#pragma unroll
            for (int g = 0; g < 16; ++g) s += red[g * 64 + t];
            atomicAdd(&colsum[t], s);
        }
    }
}

// ---------------- bucketed aggregation: one block per dest bucket (64 nodes),
// LDS accumulator 64x64 f32, edges unordered within bucket, LDS float atomics.
// X[n] = Henc[n] + sum_{e: v=n} norm_e * Henc[u_e]
__global__ __launch_bounds__(256) void k_bagg(const float* __restrict__ Henc,
                                              const int* __restrict__ base_v,
                                              const int2* __restrict__ edges,
                                              float* __restrict__ X) {
    __shared__ float acc[64 * 64];
    __shared__ int2 st[4][64];
    int t = threadIdx.x;
    int w = t >> 6, l = t & 63;
    int b = blockIdx.x;
    for (int i = t * 4; i < 4096; i += 1024) *(float4*)&acc[i] = make_float4(0.f, 0.f, 0.f, 0.f);
    __syncthreads();
    int r0 = base_v[b], r1 = base_v[b + 1];
    for (int c0 = r0 + w * 64; c0 < r1; c0 += 256) {
        int lim = min(64, r1 - c0);
        if (l < lim) st[w][l] = edges[c0 + l];
        __builtin_amdgcn_wave_barrier();
        int kk = 0;
        for (; kk + 8 <= lim; kk += 8) {
            int2 e0 = st[w][kk + 0];
            int2 e1 = st[w][kk + 1];
            int2 e2 = st[w][kk + 2];
            int2 e3 = st[w][kk + 3];
            int2 e4 = st[w][kk + 4];
            int2 e5 = st[w][kk + 5];
            int2 e6 = st[w][kk + 6];
            int2 e7 = st[w][kk + 7];
            float h0 = Henc[((e0.x & 0xFFFF) << 6) + l];
            float h1 = Henc[((e1.x & 0xFFFF) << 6) + l];
            float h2 = Henc[((e2.x & 0xFFFF) << 6) + l];
            float h3 = Henc[((e3.x & 0xFFFF) << 6) + l];
            float h4 = Henc[((e4.x & 0xFFFF) << 6) + l];
            float h5 = Henc[((e5.x & 0xFFFF) << 6) + l];
            float h6 = Henc[((e6.x & 0xFFFF) << 6) + l];
            float h7 = Henc[((e7.x & 0xFFFF) << 6) + l];
            atomicAdd(&acc[((e0.x >> 16) << 6) + l], __int_as_float(e0.y) * h0);
            atomicAdd(&acc[((e1.x >> 16) << 6) + l], __int_as_float(e1.y) * h1);
            atomicAdd(&acc[((e2.x >> 16) << 6) + l], __int_as_float(e2.y) * h2);
            atomicAdd(&acc[((e3.x >> 16) << 6) + l], __int_as_float(e3.y) * h3);
            atomicAdd(&acc[((e4.x >> 16) << 6) + l], __int_as_float(e4.y) * h4);
            atomicAdd(&acc[((e5.x >> 16) << 6) + l], __int_as_float(e5.y) * h5);
            atomicAdd(&acc[((e6.x >> 16) << 6) + l], __int_as_float(e6.y) * h6);
            atomicAdd(&acc[((e7.x >> 16) << 6) + l], __int_as_float(e7.y) * h7);
        }
        for (; kk < lim; ++kk) {
            int2 e0 = st[w][kk];
            float h0 = Henc[((e0.x & 0xFFFF) << 6) + l];
            atomicAdd(&acc[((e0.x >> 16) << 6) + l], __int_as_float(e0.y) * h0);
        }
        __builtin_amdgcn_wave_barrier();
    }
    __syncthreads();
    int n0 = b << 6;
    for (int r = w; r < 64; r += 4) {
        int n = n0 + r;
        if (n < NN) X[(size_t)n * DIM + l] = acc[(r << 6) + l] + Henc[(size_t)n * DIM + l];
    }
}

// ---------------- readout: mean + dot with out_w + out_b
__global__ void k_out(const float* __restrict__ colsum, const float* __restrict__ out_w,
                      const float* __restrict__ out_b, float* __restrict__ out) {
    int f = threadIdx.x; // 64 threads
    float v = colsum[f] * (1.0f / (float)NN) * out_w[f];
    for (int off = 32; off; off >>= 1) v += __shfl_down(v, off, 64);
    if (f == 0) out[0] = v + out_b[0];
}

extern "C" void kernel_launch(void* const* d_in, const int* in_sizes, int n_in,
                              void* d_out, int out_size, void* d_ws, size_t ws_size,
                              hipStream_t stream) {
    const float* H  = (const float*)d_in[0];
    const int*   ei = (const int*)d_in[1];
    const float* enc_w[3] = { (const float*)d_in[3], (const float*)d_in[7],  (const float*)d_in[11] };
    const float* enc_b[3] = { (const float*)d_in[4], (const float*)d_in[8],  (const float*)d_in[12] };
    const float* upd_w[3] = { (const float*)d_in[5], (const float*)d_in[9],  (const float*)d_in[13] };
    const float* upd_b[3] = { (const float*)d_in[6], (const float*)d_in[10], (const float*)d_in[14] };
    const float* out_w = (const float*)d_in[15];
    const float* out_b = (const float*)d_in[16];
    float* out = (float*)d_out;

    size_t off = 0;
    auto carve = [&](size_t bytes) {
        void* p = (char*)d_ws + off;
        off = (off + bytes + 255) & ~(size_t)255;
        return p;
    };
    int*   part_u = (int*)carve((size_t)SLICES * NB * 4);
    int*   part_v = (int*)carve((size_t)SLICES * NB * 4);
    int*   tot    = (int*)carve((size_t)2 * NB * 4);
    int*   base_u = (int*)carve((size_t)(NB + 1) * 4);
    int*   base_v = (int*)carve((size_t)(NB + 1) * 4);
    float* dis    = (float*)carve((size_t)NN * 4);
    int*   usort  = (int*)carve((size_t)NE * 4);
    int2*  edges  = (int2*)carve((size_t)NE * 8);
    float* P0     = (float*)carve((size_t)NN * DIM * 4);
    float* P1     = (float*)carve((size_t)NN * DIM * 4);
    float* P2     = (float*)carve((size_t)NN * DIM * 4);
    float* colsum = (float*)carve(64 * 4);

    hipMemsetAsync(colsum, 0, 64 * 4, stream);

    const int CB = (2 * NB + 3) / 4;   // 391 blocks for scanA/scanC
    k_bhist<<<SLICES, 256, 0, stream>>>(ei, part_u, part_v);
    k_scanA<<<CB, 256, 0, stream>>>(part_u, part_v, tot);
    k_scanB<<<1, 256, 0, stream>>>(tot, base_u, base_v);
    k_scanC<<<CB, 256, 0, stream>>>(part_u, part_v, base_u, base_v);
    k_uscat<<<SLICES, 256, 0, stream>>>(ei, part_u, usort);
    k_ucnt<<<(NB + 3) / 4, 256, 0, stream>>>(usort, base_u, dis);
    k_vscat<<<SLICES, 256, 0, stream>>>(ei, dis, part_v, edges);

    const int GB = (NN + 63) / 64;     // 782
    const float* Hin = H;
    for (int i = 0; i < 3; ++i) {
        k_gemm<<<GB, 256, 0, stream>>>(Hin, enc_w[i], enc_b[i], P0, NN, 0, nullptr);
        k_bagg<<<NB, 256, 0, stream>>>(P0, base_v, edges, P1);
        int mode = (i == 2) ? 2 : 1;
        k_gemm<<<GB, 256, 0, stream>>>(P1, upd_w[i], upd_b[i], P2, NN, mode, colsum);
        Hin = P2;
    }

    k_out<<<1, 64, 0, stream>>>(colsum, out_w, out_b, out);
}

// Round 7
// 482.906 us; speedup vs baseline: 3.9834x; 3.9834x over previous
//
#include <hip/hip_runtime.h>

#define NN 50000
#define NE 1200000
#define DIM 64
#define NB 782            // node buckets of 64: ceil(50000/64)
#define SLICES 256
#define ES 4688           // ceil(NE/SLICES)

// ---------------- coarse histograms per (slice, bucket) — LDS only
__global__ __launch_bounds__(256) void k_bhist(const int* __restrict__ ei,
                                               int* __restrict__ part_u,
                                               int* __restrict__ part_v) {
    __shared__ int hu[NB], hv[NB];
    int t = threadIdx.x, s = blockIdx.x;
    for (int i = t; i < NB; i += 256) { hu[i] = 0; hv[i] = 0; }
    __syncthreads();
    int e0 = s * ES, e1 = min(e0 + ES, NE);
    for (int e = e0 + t; e < e1; e += 256) {
        atomicAdd(&hu[ei[e] >> 6], 1);
        atomicAdd(&hv[ei[NE + e] >> 6], 1);
    }
    __syncthreads();
    for (int i = t; i < NB; i += 256) {
        part_u[s * NB + i] = hu[i];
        part_v[s * NB + i] = hv[i];
    }
}

// ---------------- column totals
__global__ __launch_bounds__(256) void k_scanA(const int* __restrict__ part_u,
                                               const int* __restrict__ part_v,
                                               int* __restrict__ tot) {
    int w = threadIdx.x >> 6, l = threadIdx.x & 63;
    int c = blockIdx.x * 4 + w;
    if (c >= 2 * NB) return;
    const int* m = (c < NB) ? part_u : part_v;
    int col = (c < NB) ? c : c - NB;
    int sum = 0;
    for (int s = l; s < SLICES; s += 64) sum += m[s * NB + col];
    for (int off = 32; off; off >>= 1) sum += __shfl_down(sum, off, 64);
    if (l == 0) tot[c] = sum;
}

// ---------------- exclusive scan of both NB-vectors
__global__ __launch_bounds__(256) void k_scanB(const int* __restrict__ tot,
                                               int* __restrict__ base_u,
                                               int* __restrict__ base_v) {
    __shared__ int sd[256];
    int t = threadIdx.x;
    for (int pass = 0; pass < 2; ++pass) {
        const int* src = tot + pass * NB;
        int* dst = pass ? base_v : base_u;
        int base = t * 4;
        int v0 = (base + 0 < NB) ? src[base + 0] : 0;
        int v1 = (base + 1 < NB) ? src[base + 1] : 0;
        int v2 = (base + 2 < NB) ? src[base + 2] : 0;
        int v3 = (base + 3 < NB) ? src[base + 3] : 0;
        int p1 = v0, p2 = v0 + v1, p3 = p2 + v2, t4 = p3 + v3;
        sd[t] = t4;
        __syncthreads();
        for (int off = 1; off < 256; off <<= 1) {
            int x = 0;
            if (t >= off) x = sd[t - off];
            __syncthreads();
            sd[t] += x;
            __syncthreads();
        }
        int excl = sd[t] - t4;
        if (base + 0 < NB) dst[base + 0] = excl;
        if (base + 1 < NB) dst[base + 1] = excl + p1;
        if (base + 2 < NB) dst[base + 2] = excl + p2;
        if (base + 3 < NB) dst[base + 3] = excl + p3;
        if (t == 255) dst[NB] = sd[255];
        __syncthreads();
    }
}

// ---------------- rebase partials: part[s][c] = base[c] + prefix over slices
__global__ __launch_bounds__(256) void k_scanC(int* __restrict__ part_u,
                                               int* __restrict__ part_v,
                                               const int* __restrict__ base_u,
                                               const int* __restrict__ base_v) {
    int w = threadIdx.x >> 6, l = threadIdx.x & 63;
    int c = blockIdx.x * 4 + w;
    if (c >= 2 * NB) return;
    int* m = (c < NB) ? part_u : part_v;
    const int* bs = (c < NB) ? base_u : base_v;
    int col = (c < NB) ? c : c - NB;
    int v0 = m[(l * 4 + 0) * NB + col];
    int v1 = m[(l * 4 + 1) * NB + col];
    int v2 = m[(l * 4 + 2) * NB + col];
    int v3 = m[(l * 4 + 3) * NB + col];
    int p1 = v0, p2 = v0 + v1, p3 = p2 + v2, t4 = p3 + v3;
    int inc = t4;
    for (int off = 1; off < 64; off <<= 1) {
        int x = __shfl_up(inc, off, 64);
        if (l >= off) inc += x;
    }
    int excl = inc - t4 + bs[col];
    m[(l * 4 + 0) * NB + col] = excl;
    m[(l * 4 + 1) * NB + col] = excl + p1;
    m[(l * 4 + 2) * NB + col] = excl + p2;
    m[(l * 4 + 3) * NB + col] = excl + p3;
}

// ---------------- scatter u into u-bucket order (LDS cursors)
__global__ __launch_bounds__(256) void k_uscat(const int* __restrict__ ei,
                                               const int* __restrict__ part_u,
                                               int* __restrict__ usort) {
    __shared__ int cur[NB];
    int t = threadIdx.x, s = blockIdx.x;
    for (int i = t; i < NB; i += 256) cur[i] = part_u[s * NB + i];
    __syncthreads();
    int e0 = s * ES, e1 = min(e0 + ES, NE);
    for (int e = e0 + t; e < e1; e += 256) {
        int u = ei[e];
        int pos = atomicAdd(&cur[u >> 6], 1);
        usort[pos] = u;
    }
}

// ---------------- per-bucket fine count of u -> dis = rsqrt(deg+1)
__global__ __launch_bounds__(256) void k_ucnt(const int* __restrict__ usort,
                                              const int* __restrict__ base_u,
                                              float* __restrict__ dis) {
    __shared__ int sh[4][64];
    int w = threadIdx.x >> 6, l = threadIdx.x & 63;
    int b = blockIdx.x * 4 + w;
    sh[w][l] = 0;
    __syncthreads();
    if (b < NB) {
        int r0 = base_u[b], r1 = base_u[b + 1];
        for (int i = r0 + l; i < r1; i += 64)
            atomicAdd(&sh[w][usort[i] & 63], 1);
    }
    __syncthreads();
    if (b < NB) {
        int n = (b << 6) + l;
        if (n < NN) dis[n] = rsqrtf((float)sh[w][l] + 1.0f);
    }
}

// ---------------- scatter edge records into v-bucket order
// record: x = u | (v&63)<<16, y = norm fp32
__global__ __launch_bounds__(256) void k_vscat(const int* __restrict__ ei,
                                               const float* __restrict__ dis,
                                               const int* __restrict__ part_v,
                                               int2* __restrict__ ebuf) {
    __shared__ int cur[NB];
    int t = threadIdx.x, s = blockIdx.x;
    for (int i = t; i < NB; i += 256) cur[i] = part_v[s * NB + i];
    __syncthreads();
    int e0 = s * ES, e1 = min(e0 + ES, NE);
    for (int e = e0 + t; e < e1; e += 256) {
        int u = ei[e], v = ei[NE + e];
        float nm = dis[u] * dis[v];
        int pos = atomicAdd(&cur[v >> 6], 1);
        ebuf[pos] = make_int2(u | ((v & 63) << 16), __float_as_int(nm));
    }
}

// ---------------- per-bucket counting sort -> node-sorted edges + row_ptr
// One wave per bucket. Final record: (u*64, norm).
__global__ __launch_bounds__(256) void k_vsort(const int2* __restrict__ ebuf,
                                               const int* __restrict__ base_v,
                                               int2* __restrict__ edges,
                                               int* __restrict__ row_ptr) {
    __shared__ int cnt[4][64];
    __shared__ int cur[4][64];
    int w = threadIdx.x >> 6, l = threadIdx.x & 63;
    int b = blockIdx.x * 4 + w;
    if (b >= NB) return;
    cnt[w][l] = 0;
    __builtin_amdgcn_wave_barrier();
    __builtin_amdgcn_s_barrier();   // harmless; waves independent but keep LDS init ordered per wave
    int r0 = base_v[b], r1 = base_v[b + 1];
    for (int i = r0 + l; i < r1; i += 64)
        atomicAdd(&cnt[w][(ebuf[i].x >> 16) & 63], 1);
    __builtin_amdgcn_wave_barrier();
    // exclusive scan of 64 counters within the wave
    int c = cnt[w][l];
    int inc = c;
    for (int off = 1; off < 64; off <<= 1) {
        int x = __shfl_up(inc, off, 64);
        if (l >= off) inc += x;
    }
    int excl = inc - c;
    cur[w][l] = r0 + excl;
    int n = (b << 6) + l;
    if (n <= NN) row_ptr[n] = r0 + excl;
    __builtin_amdgcn_wave_barrier();
    for (int i = r0 + l; i < r1; i += 64) {
        int2 rec = ebuf[i];
        int pos = atomicAdd(&cur[w][(rec.x >> 16) & 63], 1);
        edges[pos] = make_int2((rec.x & 0xFFFF) << 6, rec.y);
    }
}

// ---------------- fp32 GEMM: C = A@W + b; mode 0: store; 2: relu + colsum only
__global__ __launch_bounds__(256) void k_gemm(const float* __restrict__ A,
                                              const float* __restrict__ W,
                                              const float* __restrict__ bias,
                                              float* __restrict__ C,
                                              int M, int mode,
                                              float* __restrict__ colsum) {
    __shared__ float As[64][68];
    __shared__ float Bs[64][64];
    int t = threadIdx.x;
    int row0 = blockIdx.x * 64;
#pragma unroll
    for (int i = 0; i < 4; ++i) {
        int idx = t + i * 256;
        int r = idx >> 4, c = (idx & 15) << 2;
        float4 val = make_float4(0.f, 0.f, 0.f, 0.f);
        if (row0 + r < M) val = *(const float4*)&A[(size_t)(row0 + r) * DIM + c];
        *(float4*)&As[r][c] = val;
        *(float4*)&Bs[r][c] = *(const float4*)&W[r * DIM + c];
    }
    __syncthreads();

    int r0 = (t >> 4) * 4;
    int c0 = (t & 15) * 4;
    float acc[4][4] = {};
#pragma unroll
    for (int k = 0; k < 64; k += 4) {
        float4 b0 = *(float4*)&Bs[k + 0][c0];
        float4 b1 = *(float4*)&Bs[k + 1][c0];
        float4 b2 = *(float4*)&Bs[k + 2][c0];
        float4 b3 = *(float4*)&Bs[k + 3][c0];
#pragma unroll
        for (int i = 0; i < 4; ++i) {
            float4 av = *(float4*)&As[r0 + i][k];
            acc[i][0] = fmaf(av.x, b0.x, fmaf(av.y, b1.x, fmaf(av.z, b2.x, fmaf(av.w, b3.x, acc[i][0]))));
            acc[i][1] = fmaf(av.x, b0.y, fmaf(av.y, b1.y, fmaf(av.z, b2.y, fmaf(av.w, b3.y, acc[i][1]))));
            acc[i][2] = fmaf(av.x, b0.z, fmaf(av.y, b1.z, fmaf(av.z, b2.z, fmaf(av.w, b3.z, acc[i][2]))));
            acc[i][3] = fmaf(av.x, b0.w, fmaf(av.y, b1.w, fmaf(av.z, b2.w, fmaf(av.w, b3.w, acc[i][3]))));
        }
    }

    float4 bv = *(const float4*)&bias[c0];
    float csum[4] = {0.f, 0.f, 0.f, 0.f};
#pragma unroll
    for (int i = 0; i < 4; ++i) {
        int r = row0 + r0 + i;
        if (r < M) {
            float4 o;
            o.x = acc[i][0] + bv.x;
            o.y = acc[i][1] + bv.y;
            o.z = acc[i][2] + bv.z;
            o.w = acc[i][3] + bv.w;
            if (mode == 2) {
                o.x = fmaxf(o.x, 0.f); o.y = fmaxf(o.y, 0.f);
                o.z = fmaxf(o.z, 0.f); o.w = fmaxf(o.w, 0.f);
                csum[0] += o.x; csum[1] += o.y; csum[2] += o.z; csum[3] += o.w;
            } else {
                *(float4*)&C[(size_t)r * DIM + c0] = o;
            }
        }
    }
    if (mode == 2) {
        float* red = &As[0][0];
        __syncthreads();
        *(float4*)&red[(t >> 4) * 64 + c0] = make_float4(csum[0], csum[1], csum[2], csum[3]);
        __syncthreads();
        if (t < 64) {
            float s = 0.f;
#pragma unroll
            for (int g = 0; g < 16; ++g) s += red[g * 64 + t];
            atomicAdd(&colsum[t], s);
        }
    }
}

// ---------------- fused dual GEMM: Z = relu(X@W1+b1)@W2 + b2
__global__ __launch_bounds__(256) void k_gemm2(const float* __restrict__ X,
                                               const float* __restrict__ W1,
                                               const float* __restrict__ b1,
                                               const float* __restrict__ W2,
                                               const float* __restrict__ b2,
                                               float* __restrict__ Z, int M) {
    __shared__ float As[64][68];
    __shared__ float Bs[64][64];
    int t = threadIdx.x;
    int row0 = blockIdx.x * 64;
#pragma unroll
    for (int i = 0; i < 4; ++i) {
        int idx = t + i * 256;
        int r = idx >> 4, c = (idx & 15) << 2;
        float4 val = make_float4(0.f, 0.f, 0.f, 0.f);
        if (row0 + r < M) val = *(const float4*)&X[(size_t)(row0 + r) * DIM + c];
        *(float4*)&As[r][c] = val;
        *(float4*)&Bs[r][c] = *(const float4*)&W1[r * DIM + c];
    }
    __syncthreads();

    int r0 = (t >> 4) * 4;
    int c0 = (t & 15) * 4;
    float acc[4][4] = {};
#pragma unroll
    for (int k = 0; k < 64; k += 4) {
        float4 v0 = *(float4*)&Bs[k + 0][c0];
        float4 v1 = *(float4*)&Bs[k + 1][c0];
        float4 v2 = *(float4*)&Bs[k + 2][c0];
        float4 v3 = *(float4*)&Bs[k + 3][c0];
#pragma unroll
        for (int i = 0; i < 4; ++i) {
            float4 av = *(float4*)&As[r0 + i][k];
            acc[i][0] = fmaf(av.x, v0.x, fmaf(av.y, v1.x, fmaf(av.z, v2.x, fmaf(av.w, v3.x, acc[i][0]))));
            acc[i][1] = fmaf(av.x, v0.y, fmaf(av.y, v1.y, fmaf(av.z, v2.y, fmaf(av.w, v3.y, acc[i][1]))));
            acc[i][2] = fmaf(av.x, v0.z, fmaf(av.y, v1.z, fmaf(av.z, v2.z, fmaf(av.w, v3.z, acc[i][2]))));
            acc[i][3] = fmaf(av.x, v0.w, fmaf(av.y, v1.w, fmaf(av.z, v2.w, fmaf(av.w, v3.w, acc[i][3]))));
        }
    }

    float4 bv1 = *(const float4*)&b1[c0];
    __syncthreads();   // done reading As/Bs for gemm1
#pragma unroll
    for (int i = 0; i < 4; ++i) {
        float4 y;
        y.x = fmaxf(acc[i][0] + bv1.x, 0.f);
        y.y = fmaxf(acc[i][1] + bv1.y, 0.f);
        y.z = fmaxf(acc[i][2] + bv1.z, 0.f);
        y.w = fmaxf(acc[i][3] + bv1.w, 0.f);
        *(float4*)&As[r0 + i][c0] = y;   // Y tile replaces X
    }
#pragma unroll
    for (int i = 0; i < 4; ++i) {
        int idx = t + i * 256;
        int r = idx >> 4, c = (idx & 15) << 2;
        *(float4*)&Bs[r][c] = *(const float4*)&W2[r * DIM + c];
    }
    __syncthreads();

    float acc2[4][4] = {};
#pragma unroll
    for (int k = 0; k < 64; k += 4) {
        float4 v0 = *(float4*)&Bs[k + 0][c0];
        float4 v1 = *(float4*)&Bs[k + 1][c0];
        float4 v2 = *(float4*)&Bs[k + 2][c0];
        float4 v3 = *(float4*)&Bs[k + 3][c0];
#pragma unroll
        for (int i = 0; i < 4; ++i) {
            float4 av = *(float4*)&As[r0 + i][k];
            acc2[i][0] = fmaf(av.x, v0.x, fmaf(av.y, v1.x, fmaf(av.z, v2.x, fmaf(av.w, v3.x, acc2[i][0]))));
            acc2[i][1] = fmaf(av.x, v0.y, fmaf(av.y, v1.y, fmaf(av.z, v2.y, fmaf(av.w, v3.y, acc2[i][1]))));
            acc2[i][2] = fmaf(av.x, v0.z, fmaf(av.y, v1.z, fmaf(av.z, v2.z, fmaf(av.w, v3.z, acc2[i][2]))));
            acc2[i][3] = fmaf(av.x, v0.w, fmaf(av.y, v1.w, fmaf(av.z, v2.w, fmaf(av.w, v3.w, acc2[i][3]))));
        }
    }
    float4 bv2 = *(const float4*)&b2[c0];
#pragma unroll
    for (int i = 0; i < 4; ++i) {
        int r = row0 + r0 + i;
        if (r < M) {
            float4 o;
            o.x = acc2[i][0] + bv2.x;
            o.y = acc2[i][1] + bv2.y;
            o.z = acc2[i][2] + bv2.z;
            o.w = acc2[i][3] + bv2.w;
            *(float4*)&Z[(size_t)r * DIM + c0] = o;
        }
    }
}

// ---------------- aggregation: wave per node, register accumulate, 16-deep pipeline
__global__ __launch_bounds__(256) void k_agg(const float* __restrict__ Henc,
                                             const int* __restrict__ row_ptr,
                                             const int2* __restrict__ edges,
                                             float* __restrict__ X) {
    __shared__ int2 se[4][64];
    int w = threadIdx.x >> 6;
    int l = threadIdx.x & 63;
    int node = (blockIdx.x << 2) + w;
    if (node >= NN) return;
    int start = row_ptr[node];
    int num = row_ptr[node + 1] - start;
    float acc = 0.f;
    for (int base = 0; base < num; base += 64) {
        int lim = min(64, num - base);
        if (l < lim) se[w][l] = edges[start + base + l];
        __builtin_amdgcn_wave_barrier();
        int kk = 0;
        for (; kk + 16 <= lim; kk += 16) {
            int2 e0 = se[w][kk + 0];  int2 e1 = se[w][kk + 1];
            int2 e2 = se[w][kk + 2];  int2 e3 = se[w][kk + 3];
            int2 e4 = se[w][kk + 4];  int2 e5 = se[w][kk + 5];
            int2 e6 = se[w][kk + 6];  int2 e7 = se[w][kk + 7];
            int2 e8 = se[w][kk + 8];  int2 e9 = se[w][kk + 9];
            int2 ea = se[w][kk + 10]; int2 eb = se[w][kk + 11];
            int2 ec = se[w][kk + 12]; int2 ed = se[w][kk + 13];
            int2 ee = se[w][kk + 14]; int2 ef = se[w][kk + 15];
            float h0 = Henc[e0.x + l]; float h1 = Henc[e1.x + l];
            float h2 = Henc[e2.x + l]; float h3 = Henc[e3.x + l];
            float h4 = Henc[e4.x + l]; float h5 = Henc[e5.x + l];
            float h6 = Henc[e6.x + l]; float h7 = Henc[e7.x + l];
            float h8 = Henc[e8.x + l]; float h9 = Henc[e9.x + l];
            float ha = Henc[ea.x + l]; float hb = Henc[eb.x + l];
            float hc = Henc[ec.x + l]; float hd = Henc[ed.x + l];
            float he = Henc[ee.x + l]; float hf = Henc[ef.x + l];
            acc = fmaf(__int_as_float(e0.y), h0, acc);
            acc = fmaf(__int_as_float(e1.y), h1, acc);
            acc = fmaf(__int_as_float(e2.y), h2, acc);
            acc = fmaf(__int_as_float(e3.y), h3, acc);
            acc = fmaf(__int_as_float(e4.y), h4, acc);
            acc = fmaf(__int_as_float(e5.y), h5, acc);
            acc = fmaf(__int_as_float(e6.y), h6, acc);
            acc = fmaf(__int_as_float(e7.y), h7, acc);
            acc = fmaf(__int_as_float(e8.y), h8, acc);
            acc = fmaf(__int_as_float(e9.y), h9, acc);
            acc = fmaf(__int_as_float(ea.y), ha, acc);
            acc = fmaf(__int_as_float(eb.y), hb, acc);
            acc = fmaf(__int_as_float(ec.y), hc, acc);
            acc = fmaf(__int_as_float(ed.y), hd, acc);
            acc = fmaf(__int_as_float(ee.y), he, acc);
            acc = fmaf(__int_as_float(ef.y), hf, acc);
        }
        for (; kk + 4 <= lim; kk += 4) {
            int2 e0 = se[w][kk + 0]; int2 e1 = se[w][kk + 1];
            int2 e2 = se[w][kk + 2]; int2 e3 = se[w][kk + 3];
            float h0 = Henc[e0.x + l]; float h1 = Henc[e1.x + l];
            float h2 = Henc[e2.x + l]; float h3 = Henc[e3.x + l];
            acc = fmaf(__int_as_float(e0.y), h0, acc);
            acc = fmaf(__int_as_float(e1.y), h1, acc);
            acc = fmaf(__int_as_float(e2.y), h2, acc);
            acc = fmaf(__int_as_float(e3.y), h3, acc);
        }
        for (; kk < lim; ++kk) {
            int2 e0 = se[w][kk];
            acc = fmaf(__int_as_float(e0.y), Henc[e0.x + l], acc);
        }
        __builtin_amdgcn_wave_barrier();
    }
    X[(size_t)node * DIM + l] = acc + Henc[(size_t)node * DIM + l];
}

// ---------------- readout
__global__ void k_out(const float* __restrict__ colsum, const float* __restrict__ out_w,
                      const float* __restrict__ out_b, float* __restrict__ out) {
    int f = threadIdx.x;
    float v = colsum[f] * (1.0f / (float)NN) * out_w[f];
    for (int off = 32; off; off >>= 1) v += __shfl_down(v, off, 64);
    if (f == 0) out[0] = v + out_b[0];
}

extern "C" void kernel_launch(void* const* d_in, const int* in_sizes, int n_in,
                              void* d_out, int out_size, void* d_ws, size_t ws_size,
                              hipStream_t stream) {
    const float* H  = (const float*)d_in[0];
    const int*   ei = (const int*)d_in[1];
    const float* enc_w[3] = { (const float*)d_in[3], (const float*)d_in[7],  (const float*)d_in[11] };
    const float* enc_b[3] = { (const float*)d_in[4], (const float*)d_in[8],  (const float*)d_in[12] };
    const float* upd_w[3] = { (const float*)d_in[5], (const float*)d_in[9],  (const float*)d_in[13] };
    const float* upd_b[3] = { (const float*)d_in[6], (const float*)d_in[10], (const float*)d_in[14] };
    const float* out_w = (const float*)d_in[15];
    const float* out_b = (const float*)d_in[16];
    float* out = (float*)d_out;

    size_t off = 0;
    auto carve = [&](size_t bytes) {
        void* p = (char*)d_ws + off;
        off = (off + bytes + 255) & ~(size_t)255;
        return p;
    };
    int*   part_u  = (int*)carve((size_t)SLICES * NB * 4);
    int*   part_v  = (int*)carve((size_t)SLICES * NB * 4);
    int*   tot     = (int*)carve((size_t)2 * NB * 4);
    int*   base_u  = (int*)carve((size_t)(NB + 1) * 4);
    int*   base_v  = (int*)carve((size_t)(NB + 1) * 4);
    float* dis     = (float*)carve((size_t)NN * 4);
    int*   usort   = (int*)carve((size_t)NE * 4);
    int2*  ebuf    = (int2*)carve((size_t)NE * 8);
    int2*  edges   = (int2*)carve((size_t)NE * 8);
    int*   row_ptr = (int*)carve((size_t)(NN + 64) * 4);
    float* P0      = (float*)carve((size_t)NN * DIM * 4);
    float* P1      = (float*)carve((size_t)NN * DIM * 4);
    float* colsum  = (float*)carve(64 * 4);

    hipMemsetAsync(colsum, 0, 64 * 4, stream);

    const int CB = (2 * NB + 3) / 4;
    k_bhist<<<SLICES, 256, 0, stream>>>(ei, part_u, part_v);
    k_scanA<<<CB, 256, 0, stream>>>(part_u, part_v, tot);
    k_scanB<<<1, 256, 0, stream>>>(tot, base_u, base_v);
    k_scanC<<<CB, 256, 0, stream>>>(part_u, part_v, base_u, base_v);
    k_uscat<<<SLICES, 256, 0, stream>>>(ei, part_u, usort);
    k_ucnt<<<(NB + 3) / 4, 256, 0, stream>>>(usort, base_u, dis);
    k_vscat<<<SLICES, 256, 0, stream>>>(ei, dis, part_v, ebuf);
    k_vsort<<<(NB + 3) / 4, 256, 0, stream>>>(ebuf, base_v, edges, row_ptr);

    const int GB = (NN + 63) / 64;   // 782
    const int AB = (NN + 3) / 4;     // 12500

    k_gemm<<<GB, 256, 0, stream>>>(H, enc_w[0], enc_b[0], P0, NN, 0, nullptr);
    k_agg<<<AB, 256, 0, stream>>>(P0, row_ptr, edges, P1);
    k_gemm2<<<GB, 256, 0, stream>>>(P1, upd_w[0], upd_b[0], enc_w[1], enc_b[1], P0, NN);
    k_agg<<<AB, 256, 0, stream>>>(P0, row_ptr, edges, P1);
    k_gemm2<<<GB, 256, 0, stream>>>(P1, upd_w[1], upd_b[1], enc_w[2], enc_b[2], P0, NN);
    k_agg<<<AB, 256, 0, stream>>>(P0, row_ptr, edges, P1);
    k_gemm<<<GB, 256, 0, stream>>>(P1, upd_w[2], upd_b[2], nullptr, NN, 2, colsum);

    k_out<<<1, 64, 0, stream>>>(colsum, out_w, out_b, out);
}

// Round 8
// 456.338 us; speedup vs baseline: 4.2153x; 1.0582x over previous
//
#include <hip/hip_runtime.h>
#include <hip/hip_fp16.h>

#define NN 50000
#define NE 1200000
#define DIM 64
#define NB 782            // node buckets of 64: ceil(50000/64)
#define SLICES 256
#define ES 4688           // ceil(NE/SLICES)

// ---------------- coarse histograms per (slice, bucket) — LDS only
__global__ __launch_bounds__(256) void k_bhist(const int* __restrict__ ei,
                                               int* __restrict__ part_u,
                                               int* __restrict__ part_v) {
    __shared__ int hu[NB], hv[NB];
    int t = threadIdx.x, s = blockIdx.x;
    for (int i = t; i < NB; i += 256) { hu[i] = 0; hv[i] = 0; }
    __syncthreads();
    int e0 = s * ES, e1 = min(e0 + ES, NE);
    for (int e = e0 + t; e < e1; e += 256) {
        atomicAdd(&hu[ei[e] >> 6], 1);
        atomicAdd(&hv[ei[NE + e] >> 6], 1);
    }
    __syncthreads();
    for (int i = t; i < NB; i += 256) {
        part_u[s * NB + i] = hu[i];
        part_v[s * NB + i] = hv[i];
    }
}

// ---------------- column totals
__global__ __launch_bounds__(256) void k_scanA(const int* __restrict__ part_u,
                                               const int* __restrict__ part_v,
                                               int* __restrict__ tot) {
    int w = threadIdx.x >> 6, l = threadIdx.x & 63;
    int c = blockIdx.x * 4 + w;
    if (c >= 2 * NB) return;
    const int* m = (c < NB) ? part_u : part_v;
    int col = (c < NB) ? c : c - NB;
    int sum = 0;
    for (int s = l; s < SLICES; s += 64) sum += m[s * NB + col];
    for (int off = 32; off; off >>= 1) sum += __shfl_down(sum, off, 64);
    if (l == 0) tot[c] = sum;
}

// ---------------- exclusive scan of both NB-vectors
__global__ __launch_bounds__(256) void k_scanB(const int* __restrict__ tot,
                                               int* __restrict__ base_u,
                                               int* __restrict__ base_v) {
    __shared__ int sd[256];
    int t = threadIdx.x;
    for (int pass = 0; pass < 2; ++pass) {
        const int* src = tot + pass * NB;
        int* dst = pass ? base_v : base_u;
        int base = t * 4;
        int v0 = (base + 0 < NB) ? src[base + 0] : 0;
        int v1 = (base + 1 < NB) ? src[base + 1] : 0;
        int v2 = (base + 2 < NB) ? src[base + 2] : 0;
        int v3 = (base + 3 < NB) ? src[base + 3] : 0;
        int p1 = v0, p2 = v0 + v1, p3 = p2 + v2, t4 = p3 + v3;
        sd[t] = t4;
        __syncthreads();
        for (int off = 1; off < 256; off <<= 1) {
            int x = 0;
            if (t >= off) x = sd[t - off];
            __syncthreads();
            sd[t] += x;
            __syncthreads();
        }
        int excl = sd[t] - t4;
        if (base + 0 < NB) dst[base + 0] = excl;
        if (base + 1 < NB) dst[base + 1] = excl + p1;
        if (base + 2 < NB) dst[base + 2] = excl + p2;
        if (base + 3 < NB) dst[base + 3] = excl + p3;
        if (t == 255) dst[NB] = sd[255];
        __syncthreads();
    }
}

// ---------------- rebase partials: part[s][c] = base[c] + prefix over slices
__global__ __launch_bounds__(256) void k_scanC(int* __restrict__ part_u,
                                               int* __restrict__ part_v,
                                               const int* __restrict__ base_u,
                                               const int* __restrict__ base_v) {
    int w = threadIdx.x >> 6, l = threadIdx.x & 63;
    int c = blockIdx.x * 4 + w;
    if (c >= 2 * NB) return;
    int* m = (c < NB) ? part_u : part_v;
    const int* bs = (c < NB) ? base_u : base_v;
    int col = (c < NB) ? c : c - NB;
    int v0 = m[(l * 4 + 0) * NB + col];
    int v1 = m[(l * 4 + 1) * NB + col];
    int v2 = m[(l * 4 + 2) * NB + col];
    int v3 = m[(l * 4 + 3) * NB + col];
    int p1 = v0, p2 = v0 + v1, p3 = p2 + v2, t4 = p3 + v3;
    int inc = t4;
    for (int off = 1; off < 64; off <<= 1) {
        int x = __shfl_up(inc, off, 64);
        if (l >= off) inc += x;
    }
    int excl = inc - t4 + bs[col];
    m[(l * 4 + 0) * NB + col] = excl;
    m[(l * 4 + 1) * NB + col] = excl + p1;
    m[(l * 4 + 2) * NB + col] = excl + p2;
    m[(l * 4 + 3) * NB + col] = excl + p3;
}

// ---------------- single-pass scatter: u-keys (ushort) + v-records (u | v6<<16)
__global__ __launch_bounds__(256) void k_scat(const int* __restrict__ ei,
                                              const int* __restrict__ part_u,
                                              const int* __restrict__ part_v,
                                              ushort* __restrict__ usort,
                                              int* __restrict__ ebuf) {
    __shared__ int cu[NB], cv[NB];
    int t = threadIdx.x, s = blockIdx.x;
    for (int i = t; i < NB; i += 256) {
        cu[i] = part_u[s * NB + i];
        cv[i] = part_v[s * NB + i];
    }
    __syncthreads();
    int e0 = s * ES, e1 = min(e0 + ES, NE);
    for (int e = e0 + t; e < e1; e += 256) {
        int u = ei[e], v = ei[NE + e];
        int pu = atomicAdd(&cu[u >> 6], 1);
        usort[pu] = (ushort)u;
        int pv = atomicAdd(&cv[v >> 6], 1);
        ebuf[pv] = u | ((v & 63) << 16);
    }
}

// ---------------- per-bucket fine count of u -> dis = rsqrt(deg+1)
__global__ __launch_bounds__(256) void k_ucnt(const ushort* __restrict__ usort,
                                              const int* __restrict__ base_u,
                                              float* __restrict__ dis) {
    __shared__ int sh[4][64];
    int w = threadIdx.x >> 6, l = threadIdx.x & 63;
    int b = blockIdx.x * 4 + w;
    sh[w][l] = 0;
    __syncthreads();
    if (b < NB) {
        int r0 = base_u[b], r1 = base_u[b + 1];
        for (int i = r0 + l; i < r1; i += 64)
            atomicAdd(&sh[w][usort[i] & 63], 1);
    }
    __syncthreads();
    if (b < NB) {
        int n = (b << 6) + l;
        if (n < NN) dis[n] = rsqrtf((float)sh[w][l] + 1.0f);
    }
}

// ---------------- per-bucket counting sort -> node-sorted edges + row_ptr
// Final record: u(16b) | fp16(dis_u)(16b).
__global__ __launch_bounds__(256) void k_vsort(const int* __restrict__ ebuf,
                                               const int* __restrict__ base_v,
                                               const float* __restrict__ dis,
                                               int* __restrict__ edges,
                                               int* __restrict__ row_ptr) {
    __shared__ int cnt[4][64];
    __shared__ int cur[4][64];
    int w = threadIdx.x >> 6, l = threadIdx.x & 63;
    int b = blockIdx.x * 4 + w;
    if (b >= NB) return;
    cnt[w][l] = 0;
    __builtin_amdgcn_wave_barrier();
    int r0 = base_v[b], r1 = base_v[b + 1];
    for (int i = r0 + l; i < r1; i += 64)
        atomicAdd(&cnt[w][(ebuf[i] >> 16) & 63], 1);
    __builtin_amdgcn_wave_barrier();
    int c = cnt[w][l];
    int inc = c;
    for (int off = 1; off < 64; off <<= 1) {
        int x = __shfl_up(inc, off, 64);
        if (l >= off) inc += x;
    }
    int excl = inc - c;
    cur[w][l] = r0 + excl;
    row_ptr[(b << 6) + l] = r0 + excl;
    __builtin_amdgcn_wave_barrier();
    for (int i = r0 + l; i < r1; i += 64) {
        int rec = ebuf[i];
        int u = rec & 0xFFFF;
        int pos = atomicAdd(&cur[w][(rec >> 16) & 63], 1);
        ushort duh = __half_as_ushort(__float2half_rn(dis[u]));
        edges[pos] = u | ((int)duh << 16);
    }
}

// ---------------- GEMM (fp32 math): Ch = half(A@W + b), optional relu
__global__ __launch_bounds__(256) void k_gemm_h(const float* __restrict__ A,
                                                const float* __restrict__ W,
                                                const float* __restrict__ bias,
                                                __half* __restrict__ Ch,
                                                int M, int relu) {
    __shared__ float As[64][68];
    __shared__ float Bs[64][64];
    int t = threadIdx.x;
    int row0 = blockIdx.x * 64;
#pragma unroll
    for (int i = 0; i < 4; ++i) {
        int idx = t + i * 256;
        int r = idx >> 4, c = (idx & 15) << 2;
        float4 val = make_float4(0.f, 0.f, 0.f, 0.f);
        if (row0 + r < M) val = *(const float4*)&A[(size_t)(row0 + r) * DIM + c];
        *(float4*)&As[r][c] = val;
        *(float4*)&Bs[r][c] = *(const float4*)&W[r * DIM + c];
    }
    __syncthreads();

    int r0 = (t >> 4) * 4;
    int c0 = (t & 15) * 4;
    float acc[4][4] = {};
#pragma unroll
    for (int k = 0; k < 64; k += 4) {
        float4 b0 = *(float4*)&Bs[k + 0][c0];
        float4 b1 = *(float4*)&Bs[k + 1][c0];
        float4 b2 = *(float4*)&Bs[k + 2][c0];
        float4 b3 = *(float4*)&Bs[k + 3][c0];
#pragma unroll
        for (int i = 0; i < 4; ++i) {
            float4 av = *(float4*)&As[r0 + i][k];
            acc[i][0] = fmaf(av.x, b0.x, fmaf(av.y, b1.x, fmaf(av.z, b2.x, fmaf(av.w, b3.x, acc[i][0]))));
            acc[i][1] = fmaf(av.x, b0.y, fmaf(av.y, b1.y, fmaf(av.z, b2.y, fmaf(av.w, b3.y, acc[i][1]))));
            acc[i][2] = fmaf(av.x, b0.z, fmaf(av.y, b1.z, fmaf(av.z, b2.z, fmaf(av.w, b3.z, acc[i][2]))));
            acc[i][3] = fmaf(av.x, b0.w, fmaf(av.y, b1.w, fmaf(av.z, b2.w, fmaf(av.w, b3.w, acc[i][3]))));
        }
    }

    float4 bv = *(const float4*)&bias[c0];
#pragma unroll
    for (int i = 0; i < 4; ++i) {
        int r = row0 + r0 + i;
        if (r < M) {
            float4 o;
            o.x = acc[i][0] + bv.x;
            o.y = acc[i][1] + bv.y;
            o.z = acc[i][2] + bv.z;
            o.w = acc[i][3] + bv.w;
            if (relu) {
                o.x = fmaxf(o.x, 0.f); o.y = fmaxf(o.y, 0.f);
                o.z = fmaxf(o.z, 0.f); o.w = fmaxf(o.w, 0.f);
            }
            __half2 p0 = __floats2half2_rn(o.x, o.y);
            __half2 p1 = __floats2half2_rn(o.z, o.w);
            uint2 pk;
            pk.x = *(unsigned int*)&p0;
            pk.y = *(unsigned int*)&p1;
            *(uint2*)&Ch[(size_t)r * DIM + c0] = pk;
        }
    }
}

// ---------------- fused dual GEMM: Zh = half(relu(X@W1+b1)@W2 + b2)
__global__ __launch_bounds__(256) void k_gemm2(const float* __restrict__ X,
                                               const float* __restrict__ W1,
                                               const float* __restrict__ b1,
                                               const float* __restrict__ W2,
                                               const float* __restrict__ b2,
                                               __half* __restrict__ Zh, int M) {
    __shared__ float As[64][68];
    __shared__ float Bs[64][64];
    int t = threadIdx.x;
    int row0 = blockIdx.x * 64;
#pragma unroll
    for (int i = 0; i < 4; ++i) {
        int idx = t + i * 256;
        int r = idx >> 4, c = (idx & 15) << 2;
        float4 val = make_float4(0.f, 0.f, 0.f, 0.f);
        if (row0 + r < M) val = *(const float4*)&X[(size_t)(row0 + r) * DIM + c];
        *(float4*)&As[r][c] = val;
        *(float4*)&Bs[r][c] = *(const float4*)&W1[r * DIM + c];
    }
    __syncthreads();

    int r0 = (t >> 4) * 4;
    int c0 = (t & 15) * 4;
    float acc[4][4] = {};
#pragma unroll
    for (int k = 0; k < 64; k += 4) {
        float4 v0 = *(float4*)&Bs[k + 0][c0];
        float4 v1 = *(float4*)&Bs[k + 1][c0];
        float4 v2 = *(float4*)&Bs[k + 2][c0];
        float4 v3 = *(float4*)&Bs[k + 3][c0];
#pragma unroll
        for (int i = 0; i < 4; ++i) {
            float4 av = *(float4*)&As[r0 + i][k];
            acc[i][0] = fmaf(av.x, v0.x, fmaf(av.y, v1.x, fmaf(av.z, v2.x, fmaf(av.w, v3.x, acc[i][0]))));
            acc[i][1] = fmaf(av.x, v0.y, fmaf(av.y, v1.y, fmaf(av.z, v2.y, fmaf(av.w, v3.y, acc[i][1]))));
            acc[i][2] = fmaf(av.x, v0.z, fmaf(av.y, v1.z, fmaf(av.z, v2.z, fmaf(av.w, v3.z, acc[i][2]))));
            acc[i][3] = fmaf(av.x, v0.w, fmaf(av.y, v1.w, fmaf(av.z, v2.w, fmaf(av.w, v3.w, acc[i][3]))));
        }
    }

    float4 bv1 = *(const float4*)&b1[c0];
    __syncthreads();
#pragma unroll
    for (int i = 0; i < 4; ++i) {
        float4 y;
        y.x = fmaxf(acc[i][0] + bv1.x, 0.f);
        y.y = fmaxf(acc[i][1] + bv1.y, 0.f);
        y.z = fmaxf(acc[i][2] + bv1.z, 0.f);
        y.w = fmaxf(acc[i][3] + bv1.w, 0.f);
        *(float4*)&As[r0 + i][c0] = y;
    }
#pragma unroll
    for (int i = 0; i < 4; ++i) {
        int idx = t + i * 256;
        int r = idx >> 4, c = (idx & 15) << 2;
        *(float4*)&Bs[r][c] = *(const float4*)&W2[r * DIM + c];
    }
    __syncthreads();

    float acc2[4][4] = {};
#pragma unroll
    for (int k = 0; k < 64; k += 4) {
        float4 v0 = *(float4*)&Bs[k + 0][c0];
        float4 v1 = *(float4*)&Bs[k + 1][c0];
        float4 v2 = *(float4*)&Bs[k + 2][c0];
        float4 v3 = *(float4*)&Bs[k + 3][c0];
#pragma unroll
        for (int i = 0; i < 4; ++i) {
            float4 av = *(float4*)&As[r0 + i][k];
            acc2[i][0] = fmaf(av.x, v0.x, fmaf(av.y, v1.x, fmaf(av.z, v2.x, fmaf(av.w, v3.x, acc2[i][0]))));
            acc2[i][1] = fmaf(av.x, v0.y, fmaf(av.y, v1.y, fmaf(av.z, v2.y, fmaf(av.w, v3.y, acc2[i][1]))));
            acc2[i][2] = fmaf(av.x, v0.z, fmaf(av.y, v1.z, fmaf(av.z, v2.z, fmaf(av.w, v3.z, acc2[i][2]))));
            acc2[i][3] = fmaf(av.x, v0.w, fmaf(av.y, v1.w, fmaf(av.z, v2.w, fmaf(av.w, v3.w, acc2[i][3]))));
        }
    }
    float4 bv2 = *(const float4*)&b2[c0];
#pragma unroll
    for (int i = 0; i < 4; ++i) {
        int r = row0 + r0 + i;
        if (r < M) {
            float4 o;
            o.x = acc2[i][0] + bv2.x;
            o.y = acc2[i][1] + bv2.y;
            o.z = acc2[i][2] + bv2.z;
            o.w = acc2[i][3] + bv2.w;
            __half2 p0 = __floats2half2_rn(o.x, o.y);
            __half2 p1 = __floats2half2_rn(o.z, o.w);
            uint2 pk;
            pk.x = *(unsigned int*)&p0;
            pk.y = *(unsigned int*)&p1;
            *(uint2*)&Zh[(size_t)r * DIM + c0] = pk;
        }
    }
}

// ---------------- last GEMM: relu(X@W+b) -> column sums only
__global__ __launch_bounds__(256) void k_gemm_last(const float* __restrict__ A,
                                                   const float* __restrict__ W,
                                                   const float* __restrict__ bias,
                                                   int M, float* __restrict__ colsum) {
    __shared__ float As[64][68];
    __shared__ float Bs[64][64];
    int t = threadIdx.x;
    int row0 = blockIdx.x * 64;
#pragma unroll
    for (int i = 0; i < 4; ++i) {
        int idx = t + i * 256;
        int r = idx >> 4, c = (idx & 15) << 2;
        float4 val = make_float4(0.f, 0.f, 0.f, 0.f);
        if (row0 + r < M) val = *(const float4*)&A[(size_t)(row0 + r) * DIM + c];
        *(float4*)&As[r][c] = val;
        *(float4*)&Bs[r][c] = *(const float4*)&W[r * DIM + c];
    }
    __syncthreads();

    int r0 = (t >> 4) * 4;
    int c0 = (t & 15) * 4;
    float acc[4][4] = {};
#pragma unroll
    for (int k = 0; k < 64; k += 4) {
        float4 b0 = *(float4*)&Bs[k + 0][c0];
        float4 b1 = *(float4*)&Bs[k + 1][c0];
        float4 b2 = *(float4*)&Bs[k + 2][c0];
        float4 b3 = *(float4*)&Bs[k + 3][c0];
#pragma unroll
        for (int i = 0; i < 4; ++i) {
            float4 av = *(float4*)&As[r0 + i][k];
            acc[i][0] = fmaf(av.x, b0.x, fmaf(av.y, b1.x, fmaf(av.z, b2.x, fmaf(av.w, b3.x, acc[i][0]))));
            acc[i][1] = fmaf(av.x, b0.y, fmaf(av.y, b1.y, fmaf(av.z, b2.y, fmaf(av.w, b3.y, acc[i][1]))));
            acc[i][2] = fmaf(av.x, b0.z, fmaf(av.y, b1.z, fmaf(av.z, b2.z, fmaf(av.w, b3.z, acc[i][2]))));
            acc[i][3] = fmaf(av.x, b0.w, fmaf(av.y, b1.w, fmaf(av.z, b2.w, fmaf(av.w, b3.w, acc[i][3]))));
        }
    }

    float4 bv = *(const float4*)&bias[c0];
    float csum[4] = {0.f, 0.f, 0.f, 0.f};
#pragma unroll
    for (int i = 0; i < 4; ++i) {
        int r = row0 + r0 + i;
        if (r < M) {
            csum[0] += fmaxf(acc[i][0] + bv.x, 0.f);
            csum[1] += fmaxf(acc[i][1] + bv.y, 0.f);
            csum[2] += fmaxf(acc[i][2] + bv.z, 0.f);
            csum[3] += fmaxf(acc[i][3] + bv.w, 0.f);
        }
    }
    float* red = &As[0][0];
    __syncthreads();
    *(float4*)&red[(t >> 4) * 64 + c0] = make_float4(csum[0], csum[1], csum[2], csum[3]);
    __syncthreads();
    if (t < 64) {
        float s = 0.f;
#pragma unroll
        for (int g = 0; g < 16; ++g) s += red[g * 64 + t];
        atomicAdd(&colsum[t], s);
    }
}

// ---------------- aggregation: wave per node, fp16 row gather
// X[v] = dis_v * sum_e dis_u * Hh[u] + Hh[v]
__global__ __launch_bounds__(256) void k_agg(const __half* __restrict__ Hh,
                                             const float* __restrict__ dis,
                                             const int* __restrict__ row_ptr,
                                             const int* __restrict__ edges,
                                             float* __restrict__ X) {
    __shared__ int se[4][64];
    int w = threadIdx.x >> 6;
    int l = threadIdx.x & 63;
    int node = (blockIdx.x << 2) + w;
    if (node >= NN) return;
    int start = row_ptr[node];
    int num = row_ptr[node + 1] - start;
    float acc = 0.f;
    for (int base = 0; base < num; base += 64) {
        int lim = min(64, num - base);
        if (l < lim) se[w][l] = edges[start + base + l];
        __builtin_amdgcn_wave_barrier();
        int kk = 0;
        for (; kk + 8 <= lim; kk += 8) {
            int r0 = se[w][kk + 0]; int r1 = se[w][kk + 1];
            int r2 = se[w][kk + 2]; int r3 = se[w][kk + 3];
            int r4 = se[w][kk + 4]; int r5 = se[w][kk + 5];
            int r6 = se[w][kk + 6]; int r7 = se[w][kk + 7];
            float h0 = __half2float(Hh[((r0 & 0xFFFF) << 6) + l]);
            float h1 = __half2float(Hh[((r1 & 0xFFFF) << 6) + l]);
            float h2 = __half2float(Hh[((r2 & 0xFFFF) << 6) + l]);
            float h3 = __half2float(Hh[((r3 & 0xFFFF) << 6) + l]);
            float h4 = __half2float(Hh[((r4 & 0xFFFF) << 6) + l]);
            float h5 = __half2float(Hh[((r5 & 0xFFFF) << 6) + l]);
            float h6 = __half2float(Hh[((r6 & 0xFFFF) << 6) + l]);
            float h7 = __half2float(Hh[((r7 & 0xFFFF) << 6) + l]);
            acc = fmaf(__half2float(__ushort_as_half((ushort)(r0 >> 16) & 0xFFFFu)), h0, acc);
            acc = fmaf(__half2float(__ushort_as_half((ushort)(r1 >> 16) & 0xFFFFu)), h1, acc);
            acc = fmaf(__half2float(__ushort_as_half((ushort)(r2 >> 16) & 0xFFFFu)), h2, acc);
            acc = fmaf(__half2float(__ushort_as_half((ushort)(r3 >> 16) & 0xFFFFu)), h3, acc);
            acc = fmaf(__half2float(__ushort_as_half((ushort)(r4 >> 16) & 0xFFFFu)), h4, acc);
            acc = fmaf(__half2float(__ushort_as_half((ushort)(r5 >> 16) & 0xFFFFu)), h5, acc);
            acc = fmaf(__half2float(__ushort_as_half((ushort)(r6 >> 16) & 0xFFFFu)), h6, acc);
            acc = fmaf(__half2float(__ushort_as_half((ushort)(r7 >> 16) & 0xFFFFu)), h7, acc);
        }
        for (; kk < lim; ++kk) {
            int r0 = se[w][kk];
            float h0 = __half2float(Hh[((r0 & 0xFFFF) << 6) + l]);
            acc = fmaf(__half2float(__ushort_as_half((ushort)(r0 >> 16) & 0xFFFFu)), h0, acc);
        }
        __builtin_amdgcn_wave_barrier();
    }
    float selfv = __half2float(Hh[((size_t)node << 6) + l]);
    X[((size_t)node << 6) + l] = fmaf(dis[node], acc, selfv);
}

// ---------------- readout
__global__ void k_out(const float* __restrict__ colsum, const float* __restrict__ out_w,
                      const float* __restrict__ out_b, float* __restrict__ out) {
    int f = threadIdx.x;
    float v = colsum[f] * (1.0f / (float)NN) * out_w[f];
    for (int off = 32; off; off >>= 1) v += __shfl_down(v, off, 64);
    if (f == 0) out[0] = v + out_b[0];
}

extern "C" void kernel_launch(void* const* d_in, const int* in_sizes, int n_in,
                              void* d_out, int out_size, void* d_ws, size_t ws_size,
                              hipStream_t stream) {
    const float* H  = (const float*)d_in[0];
    const int*   ei = (const int*)d_in[1];
    const float* enc_w[3] = { (const float*)d_in[3], (const float*)d_in[7],  (const float*)d_in[11] };
    const float* enc_b[3] = { (const float*)d_in[4], (const float*)d_in[8],  (const float*)d_in[12] };
    const float* upd_w[3] = { (const float*)d_in[5], (const float*)d_in[9],  (const float*)d_in[13] };
    const float* upd_b[3] = { (const float*)d_in[6], (const float*)d_in[10], (const float*)d_in[14] };
    const float* out_w = (const float*)d_in[15];
    const float* out_b = (const float*)d_in[16];
    float* out = (float*)d_out;

    size_t off = 0;
    auto carve = [&](size_t bytes) {
        void* p = (char*)d_ws + off;
        off = (off + bytes + 255) & ~(size_t)255;
        return p;
    };
    int*    part_u  = (int*)carve((size_t)SLICES * NB * 4);
    int*    part_v  = (int*)carve((size_t)SLICES * NB * 4);
    int*    tot     = (int*)carve((size_t)2 * NB * 4);
    int*    base_u  = (int*)carve((size_t)(NB + 1) * 4);
    int*    base_v  = (int*)carve((size_t)(NB + 1) * 4);
    float*  dis     = (float*)carve((size_t)NN * 4);
    ushort* usort   = (ushort*)carve((size_t)NE * 2);
    int*    ebuf    = (int*)carve((size_t)NE * 4);
    int*    edges   = (int*)carve((size_t)NE * 4);
    int*    row_ptr = (int*)carve((size_t)(NN + 65) * 4);
    __half* Ch      = (__half*)carve((size_t)NN * DIM * 2);
    float*  X       = (float*)carve((size_t)NN * DIM * 4);
    float*  colsum  = (float*)carve(64 * 4);

    hipMemsetAsync(colsum, 0, 64 * 4, stream);

    const int CB = (2 * NB + 3) / 4;
    k_bhist<<<SLICES, 256, 0, stream>>>(ei, part_u, part_v);
    k_scanA<<<CB, 256, 0, stream>>>(part_u, part_v, tot);
    k_scanB<<<1, 256, 0, stream>>>(tot, base_u, base_v);
    k_scanC<<<CB, 256, 0, stream>>>(part_u, part_v, base_u, base_v);
    k_scat<<<SLICES, 256, 0, stream>>>(ei, part_u, part_v, usort, ebuf);
    k_ucnt<<<(NB + 3) / 4, 256, 0, stream>>>(usort, base_u, dis);
    k_vsort<<<(NB + 3) / 4, 256, 0, stream>>>(ebuf, base_v, dis, edges, row_ptr);

    const int GB = (NN + 63) / 64;   // 782
    const int AB = (NN + 3) / 4;     // 12500

    k_gemm_h<<<GB, 256, 0, stream>>>(H, enc_w[0], enc_b[0], Ch, NN, 0);
    k_agg<<<AB, 256, 0, stream>>>(Ch, dis, row_ptr, edges, X);
    k_gemm2<<<GB, 256, 0, stream>>>(X, upd_w[0], upd_b[0], enc_w[1], enc_b[1], Ch, NN);
    k_agg<<<AB, 256, 0, stream>>>(Ch, dis, row_ptr, edges, X);
    k_gemm2<<<GB, 256, 0, stream>>>(X, upd_w[1], upd_b[1], enc_w[2], enc_b[2], Ch, NN);
    k_agg<<<AB, 256, 0, stream>>>(Ch, dis, row_ptr, edges, X);
    k_gemm_last<<<GB, 256, 0, stream>>>(X, upd_w[2], upd_b[2], NN, colsum);

    k_out<<<1, 64, 0, stream>>>(colsum, out_w, out_b, out);
}

// Round 9
// 440.605 us; speedup vs baseline: 4.3658x; 1.0357x over previous
//
#include <hip/hip_runtime.h>
#include <hip/hip_fp16.h>

#define NN 50000
#define NE 1200000
#define DIM 64
#define NB 782            // node buckets of 64: ceil(50000/64)
#define SLICES 256
#define ES 4688           // ceil(NE/SLICES)

// ---------------- fused slice sort: per-slice LDS bucket-sort of u-keys and
// v-records; ALL global writes coalesced (slice-major). lpart_*[s][b] = local
// exclusive offset of bucket b's run within slice s (+[NB]=slice len).
__global__ __launch_bounds__(256) void k_lsort(const int* __restrict__ ei,
                                               ushort* __restrict__ usort,
                                               int* __restrict__ ebuf,
                                               int* __restrict__ lpart_u,
                                               int* __restrict__ lpart_v) {
    __shared__ int hist[NB + 1];
    __shared__ int scratch[256];
    __shared__ ushort sbu[ES];
    __shared__ int sbv[ES];
    int t = threadIdx.x, s = blockIdx.x;
    int e0 = s * ES, e1 = min(e0 + ES, NE), len = e1 - e0;
    int i0 = t * 4;

    // ======== pass U
    for (int i = t; i < NB; i += 256) hist[i] = 0;
    __syncthreads();
    for (int e = e0 + t; e < e1; e += 256) atomicAdd(&hist[ei[e] >> 6], 1);
    __syncthreads();
    {
        int h0 = (i0 + 0 < NB) ? hist[i0 + 0] : 0;
        int h1 = (i0 + 1 < NB) ? hist[i0 + 1] : 0;
        int h2 = (i0 + 2 < NB) ? hist[i0 + 2] : 0;
        int h3 = (i0 + 3 < NB) ? hist[i0 + 3] : 0;
        int p1 = h0, p2 = h0 + h1, p3 = p2 + h2, p4 = p3 + h3;
        scratch[t] = p4;
        __syncthreads();
        for (int off = 1; off < 256; off <<= 1) {
            int x = 0;
            if (t >= off) x = scratch[t - off];
            __syncthreads();
            scratch[t] += x;
            __syncthreads();
        }
        int excl = scratch[t] - p4;
        int* lpu = lpart_u + s * (NB + 1);
        if (i0 + 0 < NB) { lpu[i0 + 0] = excl;      hist[i0 + 0] = excl; }
        if (i0 + 1 < NB) { lpu[i0 + 1] = excl + p1; hist[i0 + 1] = excl + p1; }
        if (i0 + 2 < NB) { lpu[i0 + 2] = excl + p2; hist[i0 + 2] = excl + p2; }
        if (i0 + 3 < NB) { lpu[i0 + 3] = excl + p3; hist[i0 + 3] = excl + p3; }
        if (t == 255) lpu[NB] = scratch[255];
    }
    __syncthreads();
    for (int e = e0 + t; e < e1; e += 256) {
        int u = ei[e];
        int pos = atomicAdd(&hist[u >> 6], 1);
        sbu[pos] = (ushort)u;
    }
    __syncthreads();
    for (int i = t; i < len; i += 256) usort[e0 + i] = sbu[i];
    __syncthreads();

    // ======== pass V
    for (int i = t; i < NB; i += 256) hist[i] = 0;
    __syncthreads();
    for (int e = e0 + t; e < e1; e += 256) atomicAdd(&hist[ei[NE + e] >> 6], 1);
    __syncthreads();
    {
        int h0 = (i0 + 0 < NB) ? hist[i0 + 0] : 0;
        int h1 = (i0 + 1 < NB) ? hist[i0 + 1] : 0;
        int h2 = (i0 + 2 < NB) ? hist[i0 + 2] : 0;
        int h3 = (i0 + 3 < NB) ? hist[i0 + 3] : 0;
        int p1 = h0, p2 = h0 + h1, p3 = p2 + h2, p4 = p3 + h3;
        scratch[t] = p4;
        __syncthreads();
        for (int off = 1; off < 256; off <<= 1) {
            int x = 0;
            if (t >= off) x = scratch[t - off];
            __syncthreads();
            scratch[t] += x;
            __syncthreads();
        }
        int excl = scratch[t] - p4;
        int* lpv = lpart_v + s * (NB + 1);
        if (i0 + 0 < NB) { lpv[i0 + 0] = excl;      hist[i0 + 0] = excl; }
        if (i0 + 1 < NB) { lpv[i0 + 1] = excl + p1; hist[i0 + 1] = excl + p1; }
        if (i0 + 2 < NB) { lpv[i0 + 2] = excl + p2; hist[i0 + 2] = excl + p2; }
        if (i0 + 3 < NB) { lpv[i0 + 3] = excl + p3; hist[i0 + 3] = excl + p3; }
        if (t == 255) lpv[NB] = scratch[255];
    }
    __syncthreads();
    for (int e = e0 + t; e < e1; e += 256) {
        int u = ei[e], v = ei[NE + e];
        int pos = atomicAdd(&hist[v >> 6], 1);
        sbv[pos] = u | ((v & 63) << 16);
    }
    __syncthreads();
    for (int i = t; i < len; i += 256) ebuf[e0 + i] = sbv[i];
}

// ---------------- bucket totals from run lengths
__global__ __launch_bounds__(256) void k_scanA(const int* __restrict__ lpart_u,
                                               const int* __restrict__ lpart_v,
                                               int* __restrict__ tot) {
    int w = threadIdx.x >> 6, l = threadIdx.x & 63;
    int c = blockIdx.x * 4 + w;
    if (c >= 2 * NB) return;
    const int* lp = (c < NB) ? lpart_u : lpart_v;
    int col = (c < NB) ? c : c - NB;
    int sum = 0;
    for (int s = l; s < SLICES; s += 64) {
        const int* row = lp + s * (NB + 1);
        sum += row[col + 1] - row[col];
    }
    for (int off = 32; off; off >>= 1) sum += __shfl_down(sum, off, 64);
    if (l == 0) tot[c] = sum;
}

// ---------------- exclusive scan of both NB-vectors
__global__ __launch_bounds__(256) void k_scanB(const int* __restrict__ tot,
                                               int* __restrict__ base_u,
                                               int* __restrict__ base_v) {
    __shared__ int sd[256];
    int t = threadIdx.x;
    for (int pass = 0; pass < 2; ++pass) {
        const int* src = tot + pass * NB;
        int* dst = pass ? base_v : base_u;
        int base = t * 4;
        int v0 = (base + 0 < NB) ? src[base + 0] : 0;
        int v1 = (base + 1 < NB) ? src[base + 1] : 0;
        int v2 = (base + 2 < NB) ? src[base + 2] : 0;
        int v3 = (base + 3 < NB) ? src[base + 3] : 0;
        int p1 = v0, p2 = v0 + v1, p3 = p2 + v2, t4 = p3 + v3;
        sd[t] = t4;
        __syncthreads();
        for (int off = 1; off < 256; off <<= 1) {
            int x = 0;
            if (t >= off) x = sd[t - off];
            __syncthreads();
            sd[t] += x;
            __syncthreads();
        }
        int excl = sd[t] - t4;
        if (base + 0 < NB) dst[base + 0] = excl;
        if (base + 1 < NB) dst[base + 1] = excl + p1;
        if (base + 2 < NB) dst[base + 2] = excl + p2;
        if (base + 3 < NB) dst[base + 3] = excl + p3;
        if (t == 255) dst[NB] = sd[255];
        __syncthreads();
    }
}

// ---------------- per-bucket u count over slice runs -> dis = rsqrt(deg+1)
__global__ __launch_bounds__(256) void k_ucnt(const ushort* __restrict__ usort,
                                              const int* __restrict__ lpart_u,
                                              float* __restrict__ dis) {
    __shared__ int sh[4][64];
    int w = threadIdx.x >> 6, l = threadIdx.x & 63;
    int b = blockIdx.x * 4 + w;
    if (b >= NB) return;
    sh[w][l] = 0;
    __builtin_amdgcn_wave_barrier();
    for (int s = l; s < SLICES; s += 64) {
        const int* row = lpart_u + s * (NB + 1);
        int st = row[b], en = row[b + 1];
        for (int i = st; i < en; ++i)
            atomicAdd(&sh[w][usort[s * ES + i] & 63], 1);
    }
    __builtin_amdgcn_wave_barrier();
    int n = (b << 6) + l;
    if (n < NN) dis[n] = rsqrtf((float)sh[w][l] + 1.0f);
}

// ---------------- per-bucket counting sort over slice runs -> edges + row_ptr
// Final record: u(16b) | fp16(dis_u)(16b). Writes are bucket-contiguous (one XCD).
__global__ __launch_bounds__(256) void k_vsort(const int* __restrict__ ebuf,
                                               const int* __restrict__ lpart_v,
                                               const int* __restrict__ base_v,
                                               const float* __restrict__ dis,
                                               int* __restrict__ edges,
                                               int* __restrict__ row_ptr) {
    __shared__ int cnt[4][64];
    __shared__ int cur[4][64];
    int w = threadIdx.x >> 6, l = threadIdx.x & 63;
    int b = blockIdx.x * 4 + w;
    if (b >= NB) return;
    cnt[w][l] = 0;
    __builtin_amdgcn_wave_barrier();
    for (int s = l; s < SLICES; s += 64) {
        const int* row = lpart_v + s * (NB + 1);
        int st = row[b], en = row[b + 1];
        for (int i = st; i < en; ++i)
            atomicAdd(&cnt[w][(ebuf[s * ES + i] >> 16) & 63], 1);
    }
    __builtin_amdgcn_wave_barrier();
    int c = cnt[w][l];
    int inc = c;
    for (int off = 1; off < 64; off <<= 1) {
        int x = __shfl_up(inc, off, 64);
        if (l >= off) inc += x;
    }
    int base = base_v[b];
    int excl = inc - c;
    cur[w][l] = base + excl;
    row_ptr[(b << 6) + l] = base + excl;
    __builtin_amdgcn_wave_barrier();
    for (int s = l; s < SLICES; s += 64) {
        const int* row = lpart_v + s * (NB + 1);
        int st = row[b], en = row[b + 1];
        for (int i = st; i < en; ++i) {
            int rec = ebuf[s * ES + i];
            int u = rec & 0xFFFF;
            int pos = atomicAdd(&cur[w][(rec >> 16) & 63], 1);
            ushort dh = __half_as_ushort(__float2half_rn(dis[u]));
            edges[pos] = u | ((int)dh << 16);
        }
    }
}

// ---------------- GEMM (fp32 math): Ch = half(A@W + b)
__global__ __launch_bounds__(256) void k_gemm_h(const float* __restrict__ A,
                                                const float* __restrict__ W,
                                                const float* __restrict__ bias,
                                                __half* __restrict__ Ch, int M) {
    __shared__ float As[64][68];
    __shared__ float Bs[64][64];
    int t = threadIdx.x;
    int row0 = blockIdx.x * 64;
#pragma unroll
    for (int i = 0; i < 4; ++i) {
        int idx = t + i * 256;
        int r = idx >> 4, c = (idx & 15) << 2;
        float4 val = make_float4(0.f, 0.f, 0.f, 0.f);
        if (row0 + r < M) val = *(const float4*)&A[(size_t)(row0 + r) * DIM + c];
        *(float4*)&As[r][c] = val;
        *(float4*)&Bs[r][c] = *(const float4*)&W[r * DIM + c];
    }
    __syncthreads();
    int r0 = (t >> 4) * 4;
    int c0 = (t & 15) * 4;
    float acc[4][4] = {};
#pragma unroll
    for (int k = 0; k < 64; k += 4) {
        float4 b0 = *(float4*)&Bs[k + 0][c0];
        float4 b1 = *(float4*)&Bs[k + 1][c0];
        float4 b2 = *(float4*)&Bs[k + 2][c0];
        float4 b3 = *(float4*)&Bs[k + 3][c0];
#pragma unroll
        for (int i = 0; i < 4; ++i) {
            float4 av = *(float4*)&As[r0 + i][k];
            acc[i][0] = fmaf(av.x, b0.x, fmaf(av.y, b1.x, fmaf(av.z, b2.x, fmaf(av.w, b3.x, acc[i][0]))));
            acc[i][1] = fmaf(av.x, b0.y, fmaf(av.y, b1.y, fmaf(av.z, b2.y, fmaf(av.w, b3.y, acc[i][1]))));
            acc[i][2] = fmaf(av.x, b0.z, fmaf(av.y, b1.z, fmaf(av.z, b2.z, fmaf(av.w, b3.z, acc[i][2]))));
            acc[i][3] = fmaf(av.x, b0.w, fmaf(av.y, b1.w, fmaf(av.z, b2.w, fmaf(av.w, b3.w, acc[i][3]))));
        }
    }
    float4 bv = *(const float4*)&bias[c0];
#pragma unroll
    for (int i = 0; i < 4; ++i) {
        int r = row0 + r0 + i;
        if (r < M) {
            __half2 p0 = __floats2half2_rn(acc[i][0] + bv.x, acc[i][1] + bv.y);
            __half2 p1 = __floats2half2_rn(acc[i][2] + bv.z, acc[i][3] + bv.w);
            uint2 pk;
            pk.x = *(unsigned int*)&p0;
            pk.y = *(unsigned int*)&p1;
            *(uint2*)&Ch[(size_t)r * DIM + c0] = pk;
        }
    }
}

// ---------------- fused dual GEMM: Zh = half(relu(X@W1+b1)@W2 + b2)
__global__ __launch_bounds__(256) void k_gemm2(const float* __restrict__ X,
                                               const float* __restrict__ W1,
                                               const float* __restrict__ b1,
                                               const float* __restrict__ W2,
                                               const float* __restrict__ b2,
                                               __half* __restrict__ Zh, int M) {
    __shared__ float As[64][68];
    __shared__ float Bs[64][64];
    int t = threadIdx.x;
    int row0 = blockIdx.x * 64;
#pragma unroll
    for (int i = 0; i < 4; ++i) {
        int idx = t + i * 256;
        int r = idx >> 4, c = (idx & 15) << 2;
        float4 val = make_float4(0.f, 0.f, 0.f, 0.f);
        if (row0 + r < M) val = *(const float4*)&X[(size_t)(row0 + r) * DIM + c];
        *(float4*)&As[r][c] = val;
        *(float4*)&Bs[r][c] = *(const float4*)&W1[r * DIM + c];
    }
    __syncthreads();
    int r0 = (t >> 4) * 4;
    int c0 = (t & 15) * 4;
    float acc[4][4] = {};
#pragma unroll
    for (int k = 0; k < 64; k += 4) {
        float4 v0 = *(float4*)&Bs[k + 0][c0];
        float4 v1 = *(float4*)&Bs[k + 1][c0];
        float4 v2 = *(float4*)&Bs[k + 2][c0];
        float4 v3 = *(float4*)&Bs[k + 3][c0];
#pragma unroll
        for (int i = 0; i < 4; ++i) {
            float4 av = *(float4*)&As[r0 + i][k];
            acc[i][0] = fmaf(av.x, v0.x, fmaf(av.y, v1.x, fmaf(av.z, v2.x, fmaf(av.w, v3.x, acc[i][0]))));
            acc[i][1] = fmaf(av.x, v0.y, fmaf(av.y, v1.y, fmaf(av.z, v2.y, fmaf(av.w, v3.y, acc[i][1]))));
            acc[i][2] = fmaf(av.x, v0.z, fmaf(av.y, v1.z, fmaf(av.z, v2.z, fmaf(av.w, v3.z, acc[i][2]))));
            acc[i][3] = fmaf(av.x, v0.w, fmaf(av.y, v1.w, fmaf(av.z, v2.w, fmaf(av.w, v3.w, acc[i][3]))));
        }
    }
    float4 bv1 = *(const float4*)&b1[c0];
    __syncthreads();
#pragma unroll
    for (int i = 0; i < 4; ++i) {
        float4 y;
        y.x = fmaxf(acc[i][0] + bv1.x, 0.f);
        y.y = fmaxf(acc[i][1] + bv1.y, 0.f);
        y.z = fmaxf(acc[i][2] + bv1.z, 0.f);
        y.w = fmaxf(acc[i][3] + bv1.w, 0.f);
        *(float4*)&As[r0 + i][c0] = y;
    }
#pragma unroll
    for (int i = 0; i < 4; ++i) {
        int idx = t + i * 256;
        int r = idx >> 4, c = (idx & 15) << 2;
        *(float4*)&Bs[r][c] = *(const float4*)&W2[r * DIM + c];
    }
    __syncthreads();
    float acc2[4][4] = {};
#pragma unroll
    for (int k = 0; k < 64; k += 4) {
        float4 v0 = *(float4*)&Bs[k + 0][c0];
        float4 v1 = *(float4*)&Bs[k + 1][c0];
        float4 v2 = *(float4*)&Bs[k + 2][c0];
        float4 v3 = *(float4*)&Bs[k + 3][c0];
#pragma unroll
        for (int i = 0; i < 4; ++i) {
            float4 av = *(float4*)&As[r0 + i][k];
            acc2[i][0] = fmaf(av.x, v0.x, fmaf(av.y, v1.x, fmaf(av.z, v2.x, fmaf(av.w, v3.x, acc2[i][0]))));
            acc2[i][1] = fmaf(av.x, v0.y, fmaf(av.y, v1.y, fmaf(av.z, v2.y, fmaf(av.w, v3.y, acc2[i][1]))));
            acc2[i][2] = fmaf(av.x, v0.z, fmaf(av.y, v1.z, fmaf(av.z, v2.z, fmaf(av.w, v3.z, acc2[i][2]))));
            acc2[i][3] = fmaf(av.x, v0.w, fmaf(av.y, v1.w, fmaf(av.z, v2.w, fmaf(av.w, v3.w, acc2[i][3]))));
        }
    }
    float4 bv2 = *(const float4*)&b2[c0];
#pragma unroll
    for (int i = 0; i < 4; ++i) {
        int r = row0 + r0 + i;
        if (r < M) {
            __half2 p0 = __floats2half2_rn(acc2[i][0] + bv2.x, acc2[i][1] + bv2.y);
            __half2 p1 = __floats2half2_rn(acc2[i][2] + bv2.z, acc2[i][3] + bv2.w);
            uint2 pk;
            pk.x = *(unsigned int*)&p0;
            pk.y = *(unsigned int*)&p1;
            *(uint2*)&Zh[(size_t)r * DIM + c0] = pk;
        }
    }
}

// ---------------- last GEMM: relu(X@W+b) -> column sums only
__global__ __launch_bounds__(256) void k_gemm_last(const float* __restrict__ A,
                                                   const float* __restrict__ W,
                                                   const float* __restrict__ bias,
                                                   int M, float* __restrict__ colsum) {
    __shared__ float As[64][68];
    __shared__ float Bs[64][64];
    int t = threadIdx.x;
    int row0 = blockIdx.x * 64;
#pragma unroll
    for (int i = 0; i < 4; ++i) {
        int idx = t + i * 256;
        int r = idx >> 4, c = (idx & 15) << 2;
        float4 val = make_float4(0.f, 0.f, 0.f, 0.f);
        if (row0 + r < M) val = *(const float4*)&A[(size_t)(row0 + r) * DIM + c];
        *(float4*)&As[r][c] = val;
        *(float4*)&Bs[r][c] = *(const float4*)&W[r * DIM + c];
    }
    __syncthreads();
    int r0 = (t >> 4) * 4;
    int c0 = (t & 15) * 4;
    float acc[4][4] = {};
#pragma unroll
    for (int k = 0; k < 64; k += 4) {
        float4 b0 = *(float4*)&Bs[k + 0][c0];
        float4 b1 = *(float4*)&Bs[k + 1][c0];
        float4 b2 = *(float4*)&Bs[k + 2][c0];
        float4 b3 = *(float4*)&Bs[k + 3][c0];
#pragma unroll
        for (int i = 0; i < 4; ++i) {
            float4 av = *(float4*)&As[r0 + i][k];
            acc[i][0] = fmaf(av.x, b0.x, fmaf(av.y, b1.x, fmaf(av.z, b2.x, fmaf(av.w, b3.x, acc[i][0]))));
            acc[i][1] = fmaf(av.x, b0.y, fmaf(av.y, b1.y, fmaf(av.z, b2.y, fmaf(av.w, b3.y, acc[i][1]))));
            acc[i][2] = fmaf(av.x, b0.z, fmaf(av.y, b1.z, fmaf(av.z, b2.z, fmaf(av.w, b3.z, acc[i][2]))));
            acc[i][3] = fmaf(av.x, b0.w, fmaf(av.y, b1.w, fmaf(av.z, b2.w, fmaf(av.w, b3.w, acc[i][3]))));
        }
    }
    float4 bv = *(const float4*)&bias[c0];
    float csum[4] = {0.f, 0.f, 0.f, 0.f};
#pragma unroll
    for (int i = 0; i < 4; ++i) {
        int r = row0 + r0 + i;
        if (r < M) {
            csum[0] += fmaxf(acc[i][0] + bv.x, 0.f);
            csum[1] += fmaxf(acc[i][1] + bv.y, 0.f);
            csum[2] += fmaxf(acc[i][2] + bv.z, 0.f);
            csum[3] += fmaxf(acc[i][3] + bv.w, 0.f);
        }
    }
    float* red = &As[0][0];
    __syncthreads();
    *(float4*)&red[(t >> 4) * 64 + c0] = make_float4(csum[0], csum[1], csum[2], csum[3]);
    __syncthreads();
    if (t < 64) {
        float s = 0.f;
#pragma unroll
        for (int g = 0; g < 16; ++g) s += red[g * 64 + t];
        atomicAdd(&colsum[t], s);
    }
}

// ---------------- aggregation: wave per node, 2 edges per iteration.
// Half-wave g=0 handles edge 2j, g=1 handles edge 2j+1; lane covers 2 features
// via __half2. X[v] = dis_v * sum_e dis_u * Hh[u] + Hh[v]
__global__ __launch_bounds__(256) void k_agg(const __half2* __restrict__ Hh2,
                                             const float* __restrict__ dis,
                                             const int* __restrict__ row_ptr,
                                             const int* __restrict__ edges,
                                             float* __restrict__ X) {
    __shared__ int se[4][64];
    int w = threadIdx.x >> 6, l = threadIdx.x & 63;
    int node = (blockIdx.x << 2) + w;
    if (node >= NN) return;
    int start = row_ptr[node];
    int num = row_ptr[node + 1] - start;
    int g = l >> 5;
    int p = l & 31;
    float2 acc = {0.f, 0.f};
    for (int base = 0; base < num; base += 64) {
        int lim = min(64, num - base);
        se[w][l] = (l < lim) ? edges[start + base + l] : 0;   // rec 0 => weight +0.0
        __builtin_amdgcn_wave_barrier();
        int pairs = (lim + 1) >> 1;
        int j = 0;
        for (; j + 8 <= pairs; j += 8) {
            int rr[8];
            float2 hh[8];
#pragma unroll
            for (int q = 0; q < 8; ++q) rr[q] = se[w][2 * (j + q) + g];
#pragma unroll
            for (int q = 0; q < 8; ++q)
                hh[q] = __half22float2(Hh2[((rr[q] & 0xFFFF) << 5) + p]);
#pragma unroll
            for (int q = 0; q < 8; ++q) {
                float wt = __half2float(__ushort_as_half((ushort)((unsigned)rr[q] >> 16)));
                acc.x = fmaf(wt, hh[q].x, acc.x);
                acc.y = fmaf(wt, hh[q].y, acc.y);
            }
        }
        for (; j < pairs; ++j) {
            int r = se[w][2 * j + g];
            float2 h = __half22float2(Hh2[((r & 0xFFFF) << 5) + p]);
            float wt = __half2float(__ushort_as_half((ushort)((unsigned)r >> 16)));
            acc.x = fmaf(wt, h.x, acc.x);
            acc.y = fmaf(wt, h.y, acc.y);
        }
        __builtin_amdgcn_wave_barrier();
    }
    // combine the two half-wave accumulators
    float bx = __shfl(acc.x, p + 32, 64);
    float by = __shfl(acc.y, p + 32, 64);
    if (l < 32) {
        float2 self = __half22float2(Hh2[(node << 5) + p]);
        float dv = dis[node];
        float2 o;
        o.x = fmaf(dv, acc.x + bx, self.x);
        o.y = fmaf(dv, acc.y + by, self.y);
        *(float2*)&X[((size_t)node << 6) + (p << 1)] = o;
    }
}

// ---------------- readout
__global__ void k_out(const float* __restrict__ colsum, const float* __restrict__ out_w,
                      const float* __restrict__ out_b, float* __restrict__ out) {
    int f = threadIdx.x;
    float v = colsum[f] * (1.0f / (float)NN) * out_w[f];
    for (int off = 32; off; off >>= 1) v += __shfl_down(v, off, 64);
    if (f == 0) out[0] = v + out_b[0];
}

extern "C" void kernel_launch(void* const* d_in, const int* in_sizes, int n_in,
                              void* d_out, int out_size, void* d_ws, size_t ws_size,
                              hipStream_t stream) {
    const float* H  = (const float*)d_in[0];
    const int*   ei = (const int*)d_in[1];
    const float* enc_w[3] = { (const float*)d_in[3], (const float*)d_in[7],  (const float*)d_in[11] };
    const float* enc_b[3] = { (const float*)d_in[4], (const float*)d_in[8],  (const float*)d_in[12] };
    const float* upd_w[3] = { (const float*)d_in[5], (const float*)d_in[9],  (const float*)d_in[13] };
    const float* upd_b[3] = { (const float*)d_in[6], (const float*)d_in[10], (const float*)d_in[14] };
    const float* out_w = (const float*)d_in[15];
    const float* out_b = (const float*)d_in[16];
    float* out = (float*)d_out;

    size_t off = 0;
    auto carve = [&](size_t bytes) {
        void* p = (char*)d_ws + off;
        off = (off + bytes + 255) & ~(size_t)255;
        return p;
    };
    int*    lpart_u = (int*)carve((size_t)SLICES * (NB + 1) * 4);
    int*    lpart_v = (int*)carve((size_t)SLICES * (NB + 1) * 4);
    int*    tot     = (int*)carve((size_t)2 * NB * 4);
    int*    base_u  = (int*)carve((size_t)(NB + 1) * 4);
    int*    base_v  = (int*)carve((size_t)(NB + 1) * 4);
    float*  dis     = (float*)carve((size_t)NN * 4);
    ushort* usort   = (ushort*)carve((size_t)SLICES * ES * 2);
    int*    ebuf    = (int*)carve((size_t)SLICES * ES * 4);
    int*    edges   = (int*)carve((size_t)NE * 4);
    int*    row_ptr = (int*)carve((size_t)(NN + 65) * 4);
    __half* Ch      = (__half*)carve((size_t)NN * DIM * 2);
    float*  X       = (float*)carve((size_t)NN * DIM * 4);
    float*  colsum  = (float*)carve(64 * 4);

    hipMemsetAsync(colsum, 0, 64 * 4, stream);

    const int CB = (2 * NB + 3) / 4;   // 391
    const int BB = (NB + 3) / 4;       // 196
    k_lsort<<<SLICES, 256, 0, stream>>>(ei, usort, ebuf, lpart_u, lpart_v);
    k_scanA<<<CB, 256, 0, stream>>>(lpart_u, lpart_v, tot);
    k_scanB<<<1, 256, 0, stream>>>(tot, base_u, base_v);
    k_ucnt<<<BB, 256, 0, stream>>>(usort, lpart_u, dis);
    k_vsort<<<BB, 256, 0, stream>>>(ebuf, lpart_v, base_v, dis, edges, row_ptr);

    const int GB = (NN + 63) / 64;   // 782
    const int AB = (NN + 3) / 4;     // 12500
    const __half2* Hh2 = (const __half2*)Ch;

    k_gemm_h<<<GB, 256, 0, stream>>>(H, enc_w[0], enc_b[0], Ch, NN);
    k_agg<<<AB, 256, 0, stream>>>(Hh2, dis, row_ptr, edges, X);
    k_gemm2<<<GB, 256, 0, stream>>>(X, upd_w[0], upd_b[0], enc_w[1], enc_b[1], Ch, NN);
    k_agg<<<AB, 256, 0, stream>>>(Hh2, dis, row_ptr, edges, X);
    k_gemm2<<<GB, 256, 0, stream>>>(X, upd_w[1], upd_b[1], enc_w[2], enc_b[2], Ch, NN);
    k_agg<<<AB, 256, 0, stream>>>(Hh2, dis, row_ptr, edges, X);
    k_gemm_last<<<GB, 256, 0, stream>>>(X, upd_w[2], upd_b[2], NN, colsum);

    k_out<<<1, 64, 0, stream>>>(colsum, out_w, out_b, out);
}

// Round 10
// 419.398 us; speedup vs baseline: 4.5866x; 1.0506x over previous
//
#include <hip/hip_runtime.h>
#include <hip/hip_fp16.h>

#define NN 50000
#define NE 1200000
#define DIM 64
#define NB 782            // node buckets of 64: ceil(50000/64)
#define BB 196            // ceil(NB/4)
#define SLICES 256
#define ES 4688           // ceil(NE/SLICES)
#define VCAP 2048         // bucket cache cap (mean 1536, sd ~39 -> 13 sigma)

// ---------------- fused slice sort: per-slice LDS bucket-sort of u-keys and
// v-records; ALL global writes coalesced (slice-major).
__global__ __launch_bounds__(256) void k_lsort(const int* __restrict__ ei,
                                               ushort* __restrict__ usort,
                                               int* __restrict__ ebuf,
                                               int* __restrict__ lpart_u,
                                               int* __restrict__ lpart_v) {
    __shared__ int hist[NB + 1];
    __shared__ int scratch[256];
    __shared__ ushort sbu[ES];
    __shared__ int sbv[ES];
    int t = threadIdx.x, s = blockIdx.x;
    int e0 = s * ES, e1 = min(e0 + ES, NE), len = e1 - e0;
    int i0 = t * 4;

    // ======== pass U
    for (int i = t; i < NB; i += 256) hist[i] = 0;
    __syncthreads();
    for (int e = e0 + t; e < e1; e += 256) atomicAdd(&hist[ei[e] >> 6], 1);
    __syncthreads();
    {
        int h0 = (i0 + 0 < NB) ? hist[i0 + 0] : 0;
        int h1 = (i0 + 1 < NB) ? hist[i0 + 1] : 0;
        int h2 = (i0 + 2 < NB) ? hist[i0 + 2] : 0;
        int h3 = (i0 + 3 < NB) ? hist[i0 + 3] : 0;
        int p1 = h0, p2 = h0 + h1, p3 = p2 + h2, p4 = p3 + h3;
        scratch[t] = p4;
        __syncthreads();
        for (int off = 1; off < 256; off <<= 1) {
            int x = 0;
            if (t >= off) x = scratch[t - off];
            __syncthreads();
            scratch[t] += x;
            __syncthreads();
        }
        int excl = scratch[t] - p4;
        int* lpu = lpart_u + s * (NB + 1);
        if (i0 + 0 < NB) { lpu[i0 + 0] = excl;      hist[i0 + 0] = excl; }
        if (i0 + 1 < NB) { lpu[i0 + 1] = excl + p1; hist[i0 + 1] = excl + p1; }
        if (i0 + 2 < NB) { lpu[i0 + 2] = excl + p2; hist[i0 + 2] = excl + p2; }
        if (i0 + 3 < NB) { lpu[i0 + 3] = excl + p3; hist[i0 + 3] = excl + p3; }
        if (t == 255) lpu[NB] = scratch[255];
    }
    __syncthreads();
    for (int e = e0 + t; e < e1; e += 256) {
        int u = ei[e];
        int pos = atomicAdd(&hist[u >> 6], 1);
        sbu[pos] = (ushort)u;
    }
    __syncthreads();
    for (int i = t; i < len; i += 256) usort[e0 + i] = sbu[i];
    __syncthreads();

    // ======== pass V
    for (int i = t; i < NB; i += 256) hist[i] = 0;
    __syncthreads();
    for (int e = e0 + t; e < e1; e += 256) atomicAdd(&hist[ei[NE + e] >> 6], 1);
    __syncthreads();
    {
        int h0 = (i0 + 0 < NB) ? hist[i0 + 0] : 0;
        int h1 = (i0 + 1 < NB) ? hist[i0 + 1] : 0;
        int h2 = (i0 + 2 < NB) ? hist[i0 + 2] : 0;
        int h3 = (i0 + 3 < NB) ? hist[i0 + 3] : 0;
        int p1 = h0, p2 = h0 + h1, p3 = p2 + h2, p4 = p3 + h3;
        scratch[t] = p4;
        __syncthreads();
        for (int off = 1; off < 256; off <<= 1) {
            int x = 0;
            if (t >= off) x = scratch[t - off];
            __syncthreads();
            scratch[t] += x;
            __syncthreads();
        }
        int excl = scratch[t] - p4;
        int* lpv = lpart_v + s * (NB + 1);
        if (i0 + 0 < NB) { lpv[i0 + 0] = excl;      hist[i0 + 0] = excl; }
        if (i0 + 1 < NB) { lpv[i0 + 1] = excl + p1; hist[i0 + 1] = excl + p1; }
        if (i0 + 2 < NB) { lpv[i0 + 2] = excl + p2; hist[i0 + 2] = excl + p2; }
        if (i0 + 3 < NB) { lpv[i0 + 3] = excl + p3; hist[i0 + 3] = excl + p3; }
        if (t == 255) lpv[NB] = scratch[255];
    }
    __syncthreads();
    for (int e = e0 + t; e < e1; e += 256) {
        int u = ei[e], v = ei[NE + e];
        int pos = atomicAdd(&hist[v >> 6], 1);
        sbv[pos] = u | ((v & 63) << 16);
    }
    __syncthreads();
    for (int i = t; i < len; i += 256) ebuf[e0 + i] = sbv[i];
}

// ---------------- fused: blocks [0,BB) = per-bucket u count -> dis;
// blocks [BB,2*BB) = v-bucket totals (scanA over v only).
__global__ __launch_bounds__(256) void k_mid(const ushort* __restrict__ usort,
                                             const int* __restrict__ lpart_u,
                                             const int* __restrict__ lpart_v,
                                             float* __restrict__ dis,
                                             int* __restrict__ tot) {
    __shared__ int sh[4][64];
    int bid = blockIdx.x;
    int w = threadIdx.x >> 6, l = threadIdx.x & 63;
    if (bid < BB) {
        int b = bid * 4 + w;
        if (b >= NB) return;
        sh[w][l] = 0;
        __builtin_amdgcn_wave_barrier();
        for (int s = l; s < SLICES; s += 64) {
            const int* row = lpart_u + s * (NB + 1);
            int st = row[b], en = row[b + 1];
            for (int i = st; i < en; ++i)
                atomicAdd(&sh[w][usort[s * ES + i] & 63], 1);
        }
        __builtin_amdgcn_wave_barrier();
        int n = (b << 6) + l;
        if (n < NN) dis[n] = rsqrtf((float)sh[w][l] + 1.0f);
    } else {
        int c = (bid - BB) * 4 + w;
        if (c >= NB) return;
        int sum = 0;
        for (int s = l; s < SLICES; s += 64) {
            const int* row = lpart_v + s * (NB + 1);
            sum += row[c + 1] - row[c];
        }
        for (int off = 32; off; off >>= 1) sum += __shfl_down(sum, off, 64);
        if (l == 0) tot[c] = sum;
    }
}

// ---------------- exclusive scan of v totals -> base_v; also zero colsum
__global__ __launch_bounds__(256) void k_scanB(const int* __restrict__ tot,
                                               int* __restrict__ base_v,
                                               float* __restrict__ colsum) {
    __shared__ int sd[256];
    int t = threadIdx.x;
    if (t < 64) colsum[t] = 0.f;
    int base = t * 4;
    int v0 = (base + 0 < NB) ? tot[base + 0] : 0;
    int v1 = (base + 1 < NB) ? tot[base + 1] : 0;
    int v2 = (base + 2 < NB) ? tot[base + 2] : 0;
    int v3 = (base + 3 < NB) ? tot[base + 3] : 0;
    int p1 = v0, p2 = v0 + v1, p3 = p2 + v2, t4 = p3 + v3;
    sd[t] = t4;
    __syncthreads();
    for (int off = 1; off < 256; off <<= 1) {
        int x = 0;
        if (t >= off) x = sd[t - off];
        __syncthreads();
        sd[t] += x;
        __syncthreads();
    }
    int excl = sd[t] - t4;
    if (base + 0 < NB) base_v[base + 0] = excl;
    if (base + 1 < NB) base_v[base + 1] = excl + p1;
    if (base + 2 < NB) base_v[base + 2] = excl + p2;
    if (base + 3 < NB) base_v[base + 3] = excl + p3;
    if (t == 255) base_v[NB] = sd[255];
}

// ---------------- per-bucket counting sort, LDS-cached (single scattered read).
// Final record: u(16b) | fp16(dis_u)(16b). row_ptr written per node.
__global__ __launch_bounds__(256) void k_vsort(const int* __restrict__ ebuf,
                                               const int* __restrict__ lpart_v,
                                               const int* __restrict__ base_v,
                                               const float* __restrict__ dis,
                                               int* __restrict__ edges,
                                               int* __restrict__ row_ptr) {
    __shared__ int cache[4][VCAP];
    __shared__ int cnt[4][64];
    __shared__ int cur[4][64];
    int w = threadIdx.x >> 6, l = threadIdx.x & 63;
    int b = blockIdx.x * 4 + w;
    if (b >= NB) return;
    int rbase = base_v[b];
    int n = base_v[b + 1] - rbase;
    cnt[w][l] = 0;
    __builtin_amdgcn_wave_barrier();
    if (n <= VCAP) {
        // deterministic slice-major fill: lane l owns slices 4l..4l+3
        int len[4]; int tl = 0;
#pragma unroll
        for (int k = 0; k < 4; ++k) {
            const int* row = lpart_v + (l * 4 + k) * (NB + 1);
            len[k] = row[b + 1] - row[b];
            tl += len[k];
        }
        int inc = tl;
        for (int o = 1; o < 64; o <<= 1) {
            int x = __shfl_up(inc, o, 64);
            if (l >= o) inc += x;
        }
        int pos = inc - tl;
#pragma unroll
        for (int k = 0; k < 4; ++k) {
            int s = l * 4 + k;
            const int* row = lpart_v + s * (NB + 1);
            int st = row[b];
            for (int i = 0; i < len[k]; ++i)
                cache[w][pos++] = ebuf[s * ES + st + i];
        }
        __builtin_amdgcn_wave_barrier();
        for (int i = l; i < n; i += 64)
            atomicAdd(&cnt[w][(cache[w][i] >> 16) & 63], 1);
        __builtin_amdgcn_wave_barrier();
        int c = cnt[w][l];
        int inc2 = c;
        for (int o = 1; o < 64; o <<= 1) {
            int x = __shfl_up(inc2, o, 64);
            if (l >= o) inc2 += x;
        }
        int excl = inc2 - c;
        cur[w][l] = rbase + excl;
        row_ptr[(b << 6) + l] = rbase + excl;
        __builtin_amdgcn_wave_barrier();
        for (int i = l; i < n; i += 64) {
            int rec = cache[w][i];
            int u = rec & 0xFFFF;
            int p2 = atomicAdd(&cur[w][(rec >> 16) & 63], 1);
            ushort dh = __half_as_ushort(__float2half_rn(dis[u]));
            edges[p2] = u | ((int)dh << 16);
        }
    } else {
        // streaming fallback (two scattered passes)
        for (int s = l; s < SLICES; s += 64) {
            const int* row = lpart_v + s * (NB + 1);
            int st = row[b], en = row[b + 1];
            for (int i = st; i < en; ++i)
                atomicAdd(&cnt[w][(ebuf[s * ES + i] >> 16) & 63], 1);
        }
        __builtin_amdgcn_wave_barrier();
        int c = cnt[w][l];
        int inc2 = c;
        for (int o = 1; o < 64; o <<= 1) {
            int x = __shfl_up(inc2, o, 64);
            if (l >= o) inc2 += x;
        }
        int excl = inc2 - c;
        cur[w][l] = rbase + excl;
        row_ptr[(b << 6) + l] = rbase + excl;
        __builtin_amdgcn_wave_barrier();
        for (int s = l; s < SLICES; s += 64) {
            const int* row = lpart_v + s * (NB + 1);
            int st = row[b], en = row[b + 1];
            for (int i = st; i < en; ++i) {
                int rec = ebuf[s * ES + i];
                int u = rec & 0xFFFF;
                int p2 = atomicAdd(&cur[w][(rec >> 16) & 63], 1);
                ushort dh = __half_as_ushort(__float2half_rn(dis[u]));
                edges[p2] = u | ((int)dh << 16);
            }
        }
    }
}

// ---------------- GEMM (fp32 math): Ch = half(A@W + b)
__global__ __launch_bounds__(256) void k_gemm_h(const float* __restrict__ A,
                                                const float* __restrict__ W,
                                                const float* __restrict__ bias,
                                                __half* __restrict__ Ch, int M) {
    __shared__ float As[64][68];
    __shared__ float Bs[64][64];
    int t = threadIdx.x;
    int row0 = blockIdx.x * 64;
#pragma unroll
    for (int i = 0; i < 4; ++i) {
        int idx = t + i * 256;
        int r = idx >> 4, c = (idx & 15) << 2;
        float4 val = make_float4(0.f, 0.f, 0.f, 0.f);
        if (row0 + r < M) val = *(const float4*)&A[(size_t)(row0 + r) * DIM + c];
        *(float4*)&As[r][c] = val;
        *(float4*)&Bs[r][c] = *(const float4*)&W[r * DIM + c];
    }
    __syncthreads();
    int r0 = (t >> 4) * 4;
    int c0 = (t & 15) * 4;
    float acc[4][4] = {};
#pragma unroll
    for (int k = 0; k < 64; k += 4) {
        float4 b0 = *(float4*)&Bs[k + 0][c0];
        float4 b1 = *(float4*)&Bs[k + 1][c0];
        float4 b2 = *(float4*)&Bs[k + 2][c0];
        float4 b3 = *(float4*)&Bs[k + 3][c0];
#pragma unroll
        for (int i = 0; i < 4; ++i) {
            float4 av = *(float4*)&As[r0 + i][k];
            acc[i][0] = fmaf(av.x, b0.x, fmaf(av.y, b1.x, fmaf(av.z, b2.x, fmaf(av.w, b3.x, acc[i][0]))));
            acc[i][1] = fmaf(av.x, b0.y, fmaf(av.y, b1.y, fmaf(av.z, b2.y, fmaf(av.w, b3.y, acc[i][1]))));
            acc[i][2] = fmaf(av.x, b0.z, fmaf(av.y, b1.z, fmaf(av.z, b2.z, fmaf(av.w, b3.z, acc[i][2]))));
            acc[i][3] = fmaf(av.x, b0.w, fmaf(av.y, b1.w, fmaf(av.z, b2.w, fmaf(av.w, b3.w, acc[i][3]))));
        }
    }
    float4 bv = *(const float4*)&bias[c0];
#pragma unroll
    for (int i = 0; i < 4; ++i) {
        int r = row0 + r0 + i;
        if (r < M) {
            __half2 p0 = __floats2half2_rn(acc[i][0] + bv.x, acc[i][1] + bv.y);
            __half2 p1 = __floats2half2_rn(acc[i][2] + bv.z, acc[i][3] + bv.w);
            uint2 pk;
            pk.x = *(unsigned int*)&p0;
            pk.y = *(unsigned int*)&p1;
            *(uint2*)&Ch[(size_t)r * DIM + c0] = pk;
        }
    }
}

// ---------------- fused dual GEMM: Zh = half(relu(X@W1+b1)@W2 + b2)
__global__ __launch_bounds__(256) void k_gemm2(const float* __restrict__ X,
                                               const float* __restrict__ W1,
                                               const float* __restrict__ b1,
                                               const float* __restrict__ W2,
                                               const float* __restrict__ b2,
                                               __half* __restrict__ Zh, int M) {
    __shared__ float As[64][68];
    __shared__ float Bs[64][64];
    int t = threadIdx.x;
    int row0 = blockIdx.x * 64;
#pragma unroll
    for (int i = 0; i < 4; ++i) {
        int idx = t + i * 256;
        int r = idx >> 4, c = (idx & 15) << 2;
        float4 val = make_float4(0.f, 0.f, 0.f, 0.f);
        if (row0 + r < M) val = *(const float4*)&X[(size_t)(row0 + r) * DIM + c];
        *(float4*)&As[r][c] = val;
        *(float4*)&Bs[r][c] = *(const float4*)&W1[r * DIM + c];
    }
    __syncthreads();
    int r0 = (t >> 4) * 4;
    int c0 = (t & 15) * 4;
    float acc[4][4] = {};
#pragma unroll
    for (int k = 0; k < 64; k += 4) {
        float4 v0 = *(float4*)&Bs[k + 0][c0];
        float4 v1 = *(float4*)&Bs[k + 1][c0];
        float4 v2 = *(float4*)&Bs[k + 2][c0];
        float4 v3 = *(float4*)&Bs[k + 3][c0];
#pragma unroll
        for (int i = 0; i < 4; ++i) {
            float4 av = *(float4*)&As[r0 + i][k];
            acc[i][0] = fmaf(av.x, v0.x, fmaf(av.y, v1.x, fmaf(av.z, v2.x, fmaf(av.w, v3.x, acc[i][0]))));
            acc[i][1] = fmaf(av.x, v0.y, fmaf(av.y, v1.y, fmaf(av.z, v2.y, fmaf(av.w, v3.y, acc[i][1]))));
            acc[i][2] = fmaf(av.x, v0.z, fmaf(av.y, v1.z, fmaf(av.z, v2.z, fmaf(av.w, v3.z, acc[i][2]))));
            acc[i][3] = fmaf(av.x, v0.w, fmaf(av.y, v1.w, fmaf(av.z, v2.w, fmaf(av.w, v3.w, acc[i][3]))));
        }
    }
    float4 bv1 = *(const float4*)&b1[c0];
    __syncthreads();
#pragma unroll
    for (int i = 0; i < 4; ++i) {
        float4 y;
        y.x = fmaxf(acc[i][0] + bv1.x, 0.f);
        y.y = fmaxf(acc[i][1] + bv1.y, 0.f);
        y.z = fmaxf(acc[i][2] + bv1.z, 0.f);
        y.w = fmaxf(acc[i][3] + bv1.w, 0.f);
        *(float4*)&As[r0 + i][c0] = y;
    }
#pragma unroll
    for (int i = 0; i < 4; ++i) {
        int idx = t + i * 256;
        int r = idx >> 4, c = (idx & 15) << 2;
        *(float4*)&Bs[r][c] = *(const float4*)&W2[r * DIM + c];
    }
    __syncthreads();
    float acc2[4][4] = {};
#pragma unroll
    for (int k = 0; k < 64; k += 4) {
        float4 v0 = *(float4*)&Bs[k + 0][c0];
        float4 v1 = *(float4*)&Bs[k + 1][c0];
        float4 v2 = *(float4*)&Bs[k + 2][c0];
        float4 v3 = *(float4*)&Bs[k + 3][c0];
#pragma unroll
        for (int i = 0; i < 4; ++i) {
            float4 av = *(float4*)&As[r0 + i][k];
            acc2[i][0] = fmaf(av.x, v0.x, fmaf(av.y, v1.x, fmaf(av.z, v2.x, fmaf(av.w, v3.x, acc2[i][0]))));
            acc2[i][1] = fmaf(av.x, v0.y, fmaf(av.y, v1.y, fmaf(av.z, v2.y, fmaf(av.w, v3.y, acc2[i][1]))));
            acc2[i][2] = fmaf(av.x, v0.z, fmaf(av.y, v1.z, fmaf(av.z, v2.z, fmaf(av.w, v3.z, acc2[i][2]))));
            acc2[i][3] = fmaf(av.x, v0.w, fmaf(av.y, v1.w, fmaf(av.z, v2.w, fmaf(av.w, v3.w, acc2[i][3]))));
        }
    }
    float4 bv2 = *(const float4*)&b2[c0];
#pragma unroll
    for (int i = 0; i < 4; ++i) {
        int r = row0 + r0 + i;
        if (r < M) {
            __half2 p0 = __floats2half2_rn(acc2[i][0] + bv2.x, acc2[i][1] + bv2.y);
            __half2 p1 = __floats2half2_rn(acc2[i][2] + bv2.z, acc2[i][3] + bv2.w);
            uint2 pk;
            pk.x = *(unsigned int*)&p0;
            pk.y = *(unsigned int*)&p1;
            *(uint2*)&Zh[(size_t)r * DIM + c0] = pk;
        }
    }
}

// ---------------- last GEMM: relu(X@W+b) -> column sums only
__global__ __launch_bounds__(256) void k_gemm_last(const float* __restrict__ A,
                                                   const float* __restrict__ W,
                                                   const float* __restrict__ bias,
                                                   int M, float* __restrict__ colsum) {
    __shared__ float As[64][68];
    __shared__ float Bs[64][64];
    int t = threadIdx.x;
    int row0 = blockIdx.x * 64;
#pragma unroll
    for (int i = 0; i < 4; ++i) {
        int idx = t + i * 256;
        int r = idx >> 4, c = (idx & 15) << 2;
        float4 val = make_float4(0.f, 0.f, 0.f, 0.f);
        if (row0 + r < M) val = *(const float4*)&A[(size_t)(row0 + r) * DIM + c];
        *(float4*)&As[r][c] = val;
        *(float4*)&Bs[r][c] = *(const float4*)&W[r * DIM + c];
    }
    __syncthreads();
    int r0 = (t >> 4) * 4;
    int c0 = (t & 15) * 4;
    float acc[4][4] = {};
#pragma unroll
    for (int k = 0; k < 64; k += 4) {
        float4 b0 = *(float4*)&Bs[k + 0][c0];
        float4 b1 = *(float4*)&Bs[k + 1][c0];
        float4 b2 = *(float4*)&Bs[k + 2][c0];
        float4 b3 = *(float4*)&Bs[k + 3][c0];
#pragma unroll
        for (int i = 0; i < 4; ++i) {
            float4 av = *(float4*)&As[r0 + i][k];
            acc[i][0] = fmaf(av.x, b0.x, fmaf(av.y, b1.x, fmaf(av.z, b2.x, fmaf(av.w, b3.x, acc[i][0]))));
            acc[i][1] = fmaf(av.x, b0.y, fmaf(av.y, b1.y, fmaf(av.z, b2.y, fmaf(av.w, b3.y, acc[i][1]))));
            acc[i][2] = fmaf(av.x, b0.z, fmaf(av.y, b1.z, fmaf(av.z, b2.z, fmaf(av.w, b3.z, acc[i][2]))));
            acc[i][3] = fmaf(av.x, b0.w, fmaf(av.y, b1.w, fmaf(av.z, b2.w, fmaf(av.w, b3.w, acc[i][3]))));
        }
    }
    float4 bv = *(const float4*)&bias[c0];
    float csum[4] = {0.f, 0.f, 0.f, 0.f};
#pragma unroll
    for (int i = 0; i < 4; ++i) {
        int r = row0 + r0 + i;
        if (r < M) {
            csum[0] += fmaxf(acc[i][0] + bv.x, 0.f);
            csum[1] += fmaxf(acc[i][1] + bv.y, 0.f);
            csum[2] += fmaxf(acc[i][2] + bv.z, 0.f);
            csum[3] += fmaxf(acc[i][3] + bv.w, 0.f);
        }
    }
    float* red = &As[0][0];
    __syncthreads();
    *(float4*)&red[(t >> 4) * 64 + c0] = make_float4(csum[0], csum[1], csum[2], csum[3]);
    __syncthreads();
    if (t < 64) {
        float s = 0.f;
#pragma unroll
        for (int g = 0; g < 16; ++g) s += red[g * 64 + t];
        atomicAdd(&colsum[t], s);
    }
}

// ---------------- aggregation: wave per node, 4 edges in flight per iteration.
// Quarter-wave g handles edge 4j+g; lane covers 4 features via uint2 (half2 x2).
// X[v] = dis_v * sum_e dis_u * Hh[u] + Hh[v]
__global__ __launch_bounds__(256) void k_agg(const uint2* __restrict__ Hq,
                                             const float* __restrict__ dis,
                                             const int* __restrict__ row_ptr,
                                             const int* __restrict__ edges,
                                             float* __restrict__ X) {
    __shared__ int se[4][64];
    int w = threadIdx.x >> 6, l = threadIdx.x & 63;
    int node = (blockIdx.x << 2) + w;
    if (node >= NN) return;
    int start = row_ptr[node];
    int num = row_ptr[node + 1] - start;
    int g = l >> 4;           // edge subgroup 0..3
    int p = l & 15;           // feature quad 0..15
    float4 acc = {0.f, 0.f, 0.f, 0.f};
    for (int base = 0; base < num; base += 64) {
        int lim = min(64, num - base);
        se[w][l] = (l < lim) ? edges[start + base + l] : 0;   // rec 0 -> weight +0
        __builtin_amdgcn_wave_barrier();
        int quads = (lim + 3) >> 2;
        int j = 0;
        for (; j + 8 <= quads; j += 8) {
            int rr[8]; uint2 hh[8];
#pragma unroll
            for (int q = 0; q < 8; ++q) rr[q] = se[w][4 * (j + q) + g];
#pragma unroll
            for (int q = 0; q < 8; ++q) hh[q] = Hq[((rr[q] & 0xFFFF) << 4) + p];
#pragma unroll
            for (int q = 0; q < 8; ++q) {
                float wt = __half2float(__ushort_as_half((ushort)((unsigned)rr[q] >> 16)));
                float2 f0 = __half22float2(*(const __half2*)&hh[q].x);
                float2 f1 = __half22float2(*(const __half2*)&hh[q].y);
                acc.x = fmaf(wt, f0.x, acc.x);
                acc.y = fmaf(wt, f0.y, acc.y);
                acc.z = fmaf(wt, f1.x, acc.z);
                acc.w = fmaf(wt, f1.y, acc.w);
            }
        }
        for (; j < quads; ++j) {
            int r = se[w][4 * j + g];
            uint2 hv = Hq[((r & 0xFFFF) << 4) + p];
            float wt = __half2float(__ushort_as_half((ushort)((unsigned)r >> 16)));
            float2 f0 = __half22float2(*(const __half2*)&hv.x);
            float2 f1 = __half22float2(*(const __half2*)&hv.y);
            acc.x = fmaf(wt, f0.x, acc.x);
            acc.y = fmaf(wt, f0.y, acc.y);
            acc.z = fmaf(wt, f1.x, acc.z);
            acc.w = fmaf(wt, f1.y, acc.w);
        }
        __builtin_amdgcn_wave_barrier();
    }
    // reduce the 4 edge-subgroup partials (lanes p, p+16, p+32, p+48)
#pragma unroll
    for (int m = 16; m < 64; m <<= 1) {
        acc.x += __shfl_xor(acc.x, m, 64);
        acc.y += __shfl_xor(acc.y, m, 64);
        acc.z += __shfl_xor(acc.z, m, 64);
        acc.w += __shfl_xor(acc.w, m, 64);
    }
    if (g == 0) {
        uint2 sv = Hq[(node << 4) + p];
        float2 s0 = __half22float2(*(const __half2*)&sv.x);
        float2 s1 = __half22float2(*(const __half2*)&sv.y);
        float dv = dis[node];
        float4 o;
        o.x = fmaf(dv, acc.x, s0.x);
        o.y = fmaf(dv, acc.y, s0.y);
        o.z = fmaf(dv, acc.z, s1.x);
        o.w = fmaf(dv, acc.w, s1.y);
        *(float4*)&X[((size_t)node << 6) + (p << 2)] = o;
    }
}

// ---------------- readout
__global__ void k_out(const float* __restrict__ colsum, const float* __restrict__ out_w,
                      const float* __restrict__ out_b, float* __restrict__ out) {
    int f = threadIdx.x;
    float v = colsum[f] * (1.0f / (float)NN) * out_w[f];
    for (int off = 32; off; off >>= 1) v += __shfl_down(v, off, 64);
    if (f == 0) out[0] = v + out_b[0];
}

extern "C" void kernel_launch(void* const* d_in, const int* in_sizes, int n_in,
                              void* d_out, int out_size, void* d_ws, size_t ws_size,
                              hipStream_t stream) {
    const float* H  = (const float*)d_in[0];
    const int*   ei = (const int*)d_in[1];
    const float* enc_w[3] = { (const float*)d_in[3], (const float*)d_in[7],  (const float*)d_in[11] };
    const float* enc_b[3] = { (const float*)d_in[4], (const float*)d_in[8],  (const float*)d_in[12] };
    const float* upd_w[3] = { (const float*)d_in[5], (const float*)d_in[9],  (const float*)d_in[13] };
    const float* upd_b[3] = { (const float*)d_in[6], (const float*)d_in[10], (const float*)d_in[14] };
    const float* out_w = (const float*)d_in[15];
    const float* out_b = (const float*)d_in[16];
    float* out = (float*)d_out;

    size_t off = 0;
    auto carve = [&](size_t bytes) {
        void* p = (char*)d_ws + off;
        off = (off + bytes + 255) & ~(size_t)255;
        return p;
    };
    int*    lpart_u = (int*)carve((size_t)SLICES * (NB + 1) * 4);
    int*    lpart_v = (int*)carve((size_t)SLICES * (NB + 1) * 4);
    int*    tot     = (int*)carve((size_t)NB * 4);
    int*    base_v  = (int*)carve((size_t)(NB + 1) * 4);
    float*  dis     = (float*)carve((size_t)NN * 4);
    ushort* usort   = (ushort*)carve((size_t)SLICES * ES * 2);
    int*    ebuf    = (int*)carve((size_t)SLICES * ES * 4);
    int*    edges   = (int*)carve((size_t)NE * 4);
    int*    row_ptr = (int*)carve((size_t)(NN + 65) * 4);
    __half* Ch      = (__half*)carve((size_t)NN * DIM * 2);
    float*  X       = (float*)carve((size_t)NN * DIM * 4);
    float*  colsum  = (float*)carve(64 * 4);

    k_lsort<<<SLICES, 256, 0, stream>>>(ei, usort, ebuf, lpart_u, lpart_v);
    k_mid<<<2 * BB, 256, 0, stream>>>(usort, lpart_u, lpart_v, dis, tot);
    k_scanB<<<1, 256, 0, stream>>>(tot, base_v, colsum);
    k_vsort<<<BB, 256, 0, stream>>>(ebuf, lpart_v, base_v, dis, edges, row_ptr);

    const int GB = (NN + 63) / 64;   // 782
    const int AB = (NN + 3) / 4;     // 12500
    const uint2* Hq = (const uint2*)Ch;

    k_gemm_h<<<GB, 256, 0, stream>>>(H, enc_w[0], enc_b[0], Ch, NN);
    k_agg<<<AB, 256, 0, stream>>>(Hq, dis, row_ptr, edges, X);
    k_gemm2<<<GB, 256, 0, stream>>>(X, upd_w[0], upd_b[0], enc_w[1], enc_b[1], Ch, NN);
    k_agg<<<AB, 256, 0, stream>>>(Hq, dis, row_ptr, edges, X);
    k_gemm2<<<GB, 256, 0, stream>>>(X, upd_w[1], upd_b[1], enc_w[2], enc_b[2], Ch, NN);
    k_agg<<<AB, 256, 0, stream>>>(Hq, dis, row_ptr, edges, X);
    k_gemm_last<<<GB, 256, 0, stream>>>(X, upd_w[2], upd_b[2], NN, colsum);

    k_out<<<1, 64, 0, stream>>>(colsum, out_w, out_b, out);
}

// Round 11
// 396.815 us; speedup vs baseline: 4.8476x; 1.0569x over previous
//
#include <hip/hip_runtime.h>
#include <hip/hip_fp16.h>

#define NN 50000
#define NE 1200000
#define DIM 64
#define NB 782            // node buckets of 64: ceil(50000/64)
#define BB 196            // ceil(NB/4)
#define SLICES 256
#define ES 4688           // ceil(NE/SLICES)
#define VCAP 2048         // vsort bucket cache cap (mean 1536, ~13 sigma)
#define GB 782            // gemm blocks: ceil(NN/64)
#define FRONT_LDS 34048   // max(lsort ~32.3KB, gemm 33.8KB) rounded up

// ================= device bodies for the fused front kernel =================

// slice bucket-sort body (blocks 0..SLICES-1). smem layout:
//   hist[NB+1] | scratch[256] | sbu[ES] (ushort) | sbv[ES] (int)
__device__ __forceinline__ void lsort_body(char* smem, const int* __restrict__ ei,
                                           ushort* __restrict__ usort,
                                           int* __restrict__ ebuf,
                                           int* __restrict__ lpart_u,
                                           int* __restrict__ lpart_v) {
    int* hist = (int*)smem;                       // (NB+1)*4 = 3132 -> pad 3136
    int* scratch = (int*)(smem + 3136);           // 1024
    ushort* sbu = (ushort*)(smem + 4160);         // ES*2 = 9376
    int* sbv = (int*)(smem + 13568);              // ES*4 = 18752 (13568 16-aligned)
    int t = threadIdx.x, s = blockIdx.x;
    int e0 = s * ES, e1 = min(e0 + ES, NE), len = e1 - e0;
    int i0 = t * 4;

    // ======== pass U
    for (int i = t; i < NB; i += 256) hist[i] = 0;
    __syncthreads();
    for (int e = e0 + t; e < e1; e += 256) atomicAdd(&hist[ei[e] >> 6], 1);
    __syncthreads();
    {
        int h0 = (i0 + 0 < NB) ? hist[i0 + 0] : 0;
        int h1 = (i0 + 1 < NB) ? hist[i0 + 1] : 0;
        int h2 = (i0 + 2 < NB) ? hist[i0 + 2] : 0;
        int h3 = (i0 + 3 < NB) ? hist[i0 + 3] : 0;
        int p1 = h0, p2 = h0 + h1, p3 = p2 + h2, p4 = p3 + h3;
        scratch[t] = p4;
        __syncthreads();
        for (int off = 1; off < 256; off <<= 1) {
            int x = 0;
            if (t >= off) x = scratch[t - off];
            __syncthreads();
            scratch[t] += x;
            __syncthreads();
        }
        int excl = scratch[t] - p4;
        int* lpu = lpart_u + s * (NB + 1);
        if (i0 + 0 < NB) { lpu[i0 + 0] = excl;      hist[i0 + 0] = excl; }
        if (i0 + 1 < NB) { lpu[i0 + 1] = excl + p1; hist[i0 + 1] = excl + p1; }
        if (i0 + 2 < NB) { lpu[i0 + 2] = excl + p2; hist[i0 + 2] = excl + p2; }
        if (i0 + 3 < NB) { lpu[i0 + 3] = excl + p3; hist[i0 + 3] = excl + p3; }
        if (t == 255) lpu[NB] = scratch[255];
    }
    __syncthreads();
    for (int e = e0 + t; e < e1; e += 256) {
        int u = ei[e];
        int pos = atomicAdd(&hist[u >> 6], 1);
        sbu[pos] = (ushort)u;
    }
    __syncthreads();
    for (int i = t; i < len; i += 256) usort[e0 + i] = sbu[i];
    __syncthreads();

    // ======== pass V
    for (int i = t; i < NB; i += 256) hist[i] = 0;
    __syncthreads();
    for (int e = e0 + t; e < e1; e += 256) atomicAdd(&hist[ei[NE + e] >> 6], 1);
    __syncthreads();
    {
        int h0 = (i0 + 0 < NB) ? hist[i0 + 0] : 0;
        int h1 = (i0 + 1 < NB) ? hist[i0 + 1] : 0;
        int h2 = (i0 + 2 < NB) ? hist[i0 + 2] : 0;
        int h3 = (i0 + 3 < NB) ? hist[i0 + 3] : 0;
        int p1 = h0, p2 = h0 + h1, p3 = p2 + h2, p4 = p3 + h3;
        scratch[t] = p4;
        __syncthreads();
        for (int off = 1; off < 256; off <<= 1) {
            int x = 0;
            if (t >= off) x = scratch[t - off];
            __syncthreads();
            scratch[t] += x;
            __syncthreads();
        }
        int excl = scratch[t] - p4;
        int* lpv = lpart_v + s * (NB + 1);
        if (i0 + 0 < NB) { lpv[i0 + 0] = excl;      hist[i0 + 0] = excl; }
        if (i0 + 1 < NB) { lpv[i0 + 1] = excl + p1; hist[i0 + 1] = excl + p1; }
        if (i0 + 2 < NB) { lpv[i0 + 2] = excl + p2; hist[i0 + 2] = excl + p2; }
        if (i0 + 3 < NB) { lpv[i0 + 3] = excl + p3; hist[i0 + 3] = excl + p3; }
        if (t == 255) lpv[NB] = scratch[255];
    }
    __syncthreads();
    for (int e = e0 + t; e < e1; e += 256) {
        int u = ei[e], v = ei[NE + e];
        int pos = atomicAdd(&hist[v >> 6], 1);
        sbv[pos] = u | ((v & 63) << 16);
    }
    __syncthreads();
    for (int i = t; i < len; i += 256) ebuf[e0 + i] = sbv[i];
}

// fp32 GEMM body -> fp16 out. smem: As[64][68] | Bs[64][64]
__device__ __forceinline__ void gemm_h_body(char* smem, int blk,
                                            const float* __restrict__ A,
                                            const float* __restrict__ W,
                                            const float* __restrict__ bias,
                                            __half* __restrict__ Ch, int M) {
    float (*As)[68] = (float(*)[68])smem;                 // 17408 B
    float (*Bs)[64] = (float(*)[64])(smem + 17408);       // 16384 B
    int t = threadIdx.x;
    int row0 = blk * 64;
#pragma unroll
    for (int i = 0; i < 4; ++i) {
        int idx = t + i * 256;
        int r = idx >> 4, c = (idx & 15) << 2;
        float4 val = make_float4(0.f, 0.f, 0.f, 0.f);
        if (row0 + r < M) val = *(const float4*)&A[(size_t)(row0 + r) * DIM + c];
        *(float4*)&As[r][c] = val;
        *(float4*)&Bs[r][c] = *(const float4*)&W[r * DIM + c];
    }
    __syncthreads();
    int r0 = (t >> 4) * 4;
    int c0 = (t & 15) * 4;
    float acc[4][4] = {};
#pragma unroll
    for (int k = 0; k < 64; k += 4) {
        float4 b0 = *(float4*)&Bs[k + 0][c0];
        float4 b1 = *(float4*)&Bs[k + 1][c0];
        float4 b2 = *(float4*)&Bs[k + 2][c0];
        float4 b3 = *(float4*)&Bs[k + 3][c0];
#pragma unroll
        for (int i = 0; i < 4; ++i) {
            float4 av = *(float4*)&As[r0 + i][k];
            acc[i][0] = fmaf(av.x, b0.x, fmaf(av.y, b1.x, fmaf(av.z, b2.x, fmaf(av.w, b3.x, acc[i][0]))));
            acc[i][1] = fmaf(av.x, b0.y, fmaf(av.y, b1.y, fmaf(av.z, b2.y, fmaf(av.w, b3.y, acc[i][1]))));
            acc[i][2] = fmaf(av.x, b0.z, fmaf(av.y, b1.z, fmaf(av.z, b2.z, fmaf(av.w, b3.z, acc[i][2]))));
            acc[i][3] = fmaf(av.x, b0.w, fmaf(av.y, b1.w, fmaf(av.z, b2.w, fmaf(av.w, b3.w, acc[i][3]))));
        }
    }
    float4 bv = *(const float4*)&bias[c0];
#pragma unroll
    for (int i = 0; i < 4; ++i) {
        int r = row0 + r0 + i;
        if (r < M) {
            __half2 p0 = __floats2half2_rn(acc[i][0] + bv.x, acc[i][1] + bv.y);
            __half2 p1 = __floats2half2_rn(acc[i][2] + bv.z, acc[i][3] + bv.w);
            uint2 pk;
            pk.x = *(unsigned int*)&p0;
            pk.y = *(unsigned int*)&p1;
            *(uint2*)&Ch[(size_t)r * DIM + c0] = pk;
        }
    }
}

// fused front: blocks [0,SLICES) = slice sort; [SLICES, SLICES+GB) = enc GEMM 0
__global__ __launch_bounds__(256) void k_front(const int* __restrict__ ei,
                                               ushort* __restrict__ usort,
                                               int* __restrict__ ebuf,
                                               int* __restrict__ lpart_u,
                                               int* __restrict__ lpart_v,
                                               const float* __restrict__ A,
                                               const float* __restrict__ W,
                                               const float* __restrict__ bias,
                                               __half* __restrict__ Ch) {
    extern __shared__ char smem[];
    if (blockIdx.x < SLICES)
        lsort_body(smem, ei, usort, ebuf, lpart_u, lpart_v);
    else
        gemm_h_body(smem, blockIdx.x - SLICES, A, W, bias, Ch, NN);
}

// ---------------- fused: blocks [0,BB) = per-bucket u count -> dis;
// blocks [BB,2*BB) = v-bucket totals.
__global__ __launch_bounds__(256) void k_mid(const ushort* __restrict__ usort,
                                             const int* __restrict__ lpart_u,
                                             const int* __restrict__ lpart_v,
                                             float* __restrict__ dis,
                                             int* __restrict__ tot) {
    __shared__ int sh[4][64];
    int bid = blockIdx.x;
    int w = threadIdx.x >> 6, l = threadIdx.x & 63;
    if (bid < BB) {
        int b = bid * 4 + w;
        if (b >= NB) return;
        sh[w][l] = 0;
        __builtin_amdgcn_wave_barrier();
        for (int s = l; s < SLICES; s += 64) {
            const int* row = lpart_u + s * (NB + 1);
            int st = row[b], en = row[b + 1];
            for (int i = st; i < en; ++i)
                atomicAdd(&sh[w][usort[s * ES + i] & 63], 1);
        }
        __builtin_amdgcn_wave_barrier();
        int n = (b << 6) + l;
        if (n < NN) dis[n] = rsqrtf((float)sh[w][l] + 1.0f);
    } else {
        int c = (bid - BB) * 4 + w;
        if (c >= NB) return;
        int sum = 0;
        for (int s = l; s < SLICES; s += 64) {
            const int* row = lpart_v + s * (NB + 1);
            sum += row[c + 1] - row[c];
        }
        for (int off = 32; off; off >>= 1) sum += __shfl_down(sum, off, 64);
        if (l == 0) tot[c] = sum;
    }
}

// ---------------- exclusive scan of v totals -> base_v; zero colsum
__global__ __launch_bounds__(256) void k_scanB(const int* __restrict__ tot,
                                               int* __restrict__ base_v,
                                               float* __restrict__ colsum) {
    __shared__ int sd[256];
    int t = threadIdx.x;
    if (t < 64) colsum[t] = 0.f;
    int base = t * 4;
    int v0 = (base + 0 < NB) ? tot[base + 0] : 0;
    int v1 = (base + 1 < NB) ? tot[base + 1] : 0;
    int v2 = (base + 2 < NB) ? tot[base + 2] : 0;
    int v3 = (base + 3 < NB) ? tot[base + 3] : 0;
    int p1 = v0, p2 = v0 + v1, p3 = p2 + v2, t4 = p3 + v3;
    sd[t] = t4;
    __syncthreads();
    for (int off = 1; off < 256; off <<= 1) {
        int x = 0;
        if (t >= off) x = sd[t - off];
        __syncthreads();
        sd[t] += x;
        __syncthreads();
    }
    int excl = sd[t] - t4;
    if (base + 0 < NB) base_v[base + 0] = excl;
    if (base + 1 < NB) base_v[base + 1] = excl + p1;
    if (base + 2 < NB) base_v[base + 2] = excl + p2;
    if (base + 3 < NB) base_v[base + 3] = excl + p3;
    if (t == 255) base_v[NB] = sd[255];
}

// ---------------- per-bucket counting sort, LDS-cached.
// Final record: u(16b) | fp16(dis_u)(16b). row_ptr per node.
__global__ __launch_bounds__(256) void k_vsort(const int* __restrict__ ebuf,
                                               const int* __restrict__ lpart_v,
                                               const int* __restrict__ base_v,
                                               const float* __restrict__ dis,
                                               int* __restrict__ edges,
                                               int* __restrict__ row_ptr) {
    __shared__ int cache[4][VCAP];
    __shared__ int cnt[4][64];
    __shared__ int cur[4][64];
    int w = threadIdx.x >> 6, l = threadIdx.x & 63;
    int b = blockIdx.x * 4 + w;
    if (b >= NB) return;
    int rbase = base_v[b];
    int n = base_v[b + 1] - rbase;
    cnt[w][l] = 0;
    __builtin_amdgcn_wave_barrier();
    if (n <= VCAP) {
        int len[4]; int tl = 0;
#pragma unroll
        for (int k = 0; k < 4; ++k) {
            const int* row = lpart_v + (l * 4 + k) * (NB + 1);
            len[k] = row[b + 1] - row[b];
            tl += len[k];
        }
        int inc = tl;
        for (int o = 1; o < 64; o <<= 1) {
            int x = __shfl_up(inc, o, 64);
            if (l >= o) inc += x;
        }
        int pos = inc - tl;
#pragma unroll
        for (int k = 0; k < 4; ++k) {
            int s = l * 4 + k;
            const int* row = lpart_v + s * (NB + 1);
            int st = row[b];
            for (int i = 0; i < len[k]; ++i)
                cache[w][pos++] = ebuf[s * ES + st + i];
        }
        __builtin_amdgcn_wave_barrier();
        for (int i = l; i < n; i += 64)
            atomicAdd(&cnt[w][(cache[w][i] >> 16) & 63], 1);
        __builtin_amdgcn_wave_barrier();
        int c = cnt[w][l];
        int inc2 = c;
        for (int o = 1; o < 64; o <<= 1) {
            int x = __shfl_up(inc2, o, 64);
            if (l >= o) inc2 += x;
        }
        int excl = inc2 - c;
        cur[w][l] = rbase + excl;
        row_ptr[(b << 6) + l] = rbase + excl;
        __builtin_amdgcn_wave_barrier();
        for (int i = l; i < n; i += 64) {
            int rec = cache[w][i];
            int u = rec & 0xFFFF;
            int p2 = atomicAdd(&cur[w][(rec >> 16) & 63], 1);
            ushort dh = __half_as_ushort(__float2half_rn(dis[u]));
            edges[p2] = u | ((int)dh << 16);
        }
    } else {
        for (int s = l; s < SLICES; s += 64) {
            const int* row = lpart_v + s * (NB + 1);
            int st = row[b], en = row[b + 1];
            for (int i = st; i < en; ++i)
                atomicAdd(&cnt[w][(ebuf[s * ES + i] >> 16) & 63], 1);
        }
        __builtin_amdgcn_wave_barrier();
        int c = cnt[w][l];
        int inc2 = c;
        for (int o = 1; o < 64; o <<= 1) {
            int x = __shfl_up(inc2, o, 64);
            if (l >= o) inc2 += x;
        }
        int excl = inc2 - c;
        cur[w][l] = rbase + excl;
        row_ptr[(b << 6) + l] = rbase + excl;
        __builtin_amdgcn_wave_barrier();
        for (int s = l; s < SLICES; s += 64) {
            const int* row = lpart_v + s * (NB + 1);
            int st = row[b], en = row[b + 1];
            for (int i = st; i < en; ++i) {
                int rec = ebuf[s * ES + i];
                int u = rec & 0xFFFF;
                int p2 = atomicAdd(&cur[w][(rec >> 16) & 63], 1);
                ushort dh = __half_as_ushort(__float2half_rn(dis[u]));
                edges[p2] = u | ((int)dh << 16);
            }
        }
    }
}

// ---------------- fused dual GEMM: Zh = half(relu(X@W1+b1)@W2 + b2)
__global__ __launch_bounds__(256) void k_gemm2(const float* __restrict__ X,
                                               const float* __restrict__ W1,
                                               const float* __restrict__ b1,
                                               const float* __restrict__ W2,
                                               const float* __restrict__ b2,
                                               __half* __restrict__ Zh, int M) {
    __shared__ float As[64][68];
    __shared__ float Bs[64][64];
    int t = threadIdx.x;
    int row0 = blockIdx.x * 64;
#pragma unroll
    for (int i = 0; i < 4; ++i) {
        int idx = t + i * 256;
        int r = idx >> 4, c = (idx & 15) << 2;
        float4 val = make_float4(0.f, 0.f, 0.f, 0.f);
        if (row0 + r < M) val = *(const float4*)&X[(size_t)(row0 + r) * DIM + c];
        *(float4*)&As[r][c] = val;
        *(float4*)&Bs[r][c] = *(const float4*)&W1[r * DIM + c];
    }
    __syncthreads();
    int r0 = (t >> 4) * 4;
    int c0 = (t & 15) * 4;
    float acc[4][4] = {};
#pragma unroll
    for (int k = 0; k < 64; k += 4) {
        float4 v0 = *(float4*)&Bs[k + 0][c0];
        float4 v1 = *(float4*)&Bs[k + 1][c0];
        float4 v2 = *(float4*)&Bs[k + 2][c0];
        float4 v3 = *(float4*)&Bs[k + 3][c0];
#pragma unroll
        for (int i = 0; i < 4; ++i) {
            float4 av = *(float4*)&As[r0 + i][k];
            acc[i][0] = fmaf(av.x, v0.x, fmaf(av.y, v1.x, fmaf(av.z, v2.x, fmaf(av.w, v3.x, acc[i][0]))));
            acc[i][1] = fmaf(av.x, v0.y, fmaf(av.y, v1.y, fmaf(av.z, v2.y, fmaf(av.w, v3.y, acc[i][1]))));
            acc[i][2] = fmaf(av.x, v0.z, fmaf(av.y, v1.z, fmaf(av.z, v2.z, fmaf(av.w, v3.z, acc[i][2]))));
            acc[i][3] = fmaf(av.x, v0.w, fmaf(av.y, v1.w, fmaf(av.z, v2.w, fmaf(av.w, v3.w, acc[i][3]))));
        }
    }
    float4 bv1 = *(const float4*)&b1[c0];
    __syncthreads();
#pragma unroll
    for (int i = 0; i < 4; ++i) {
        float4 y;
        y.x = fmaxf(acc[i][0] + bv1.x, 0.f);
        y.y = fmaxf(acc[i][1] + bv1.y, 0.f);
        y.z = fmaxf(acc[i][2] + bv1.z, 0.f);
        y.w = fmaxf(acc[i][3] + bv1.w, 0.f);
        *(float4*)&As[r0 + i][c0] = y;
    }
#pragma unroll
    for (int i = 0; i < 4; ++i) {
        int idx = t + i * 256;
        int r = idx >> 4, c = (idx & 15) << 2;
        *(float4*)&Bs[r][c] = *(const float4*)&W2[r * DIM + c];
    }
    __syncthreads();
    float acc2[4][4] = {};
#pragma unroll
    for (int k = 0; k < 64; k += 4) {
        float4 v0 = *(float4*)&Bs[k + 0][c0];
        float4 v1 = *(float4*)&Bs[k + 1][c0];
        float4 v2 = *(float4*)&Bs[k + 2][c0];
        float4 v3 = *(float4*)&Bs[k + 3][c0];
#pragma unroll
        for (int i = 0; i < 4; ++i) {
            float4 av = *(float4*)&As[r0 + i][k];
            acc2[i][0] = fmaf(av.x, v0.x, fmaf(av.y, v1.x, fmaf(av.z, v2.x, fmaf(av.w, v3.x, acc2[i][0]))));
            acc2[i][1] = fmaf(av.x, v0.y, fmaf(av.y, v1.y, fmaf(av.z, v2.y, fmaf(av.w, v3.y, acc2[i][1]))));
            acc2[i][2] = fmaf(av.x, v0.z, fmaf(av.y, v1.z, fmaf(av.z, v2.z, fmaf(av.w, v3.z, acc2[i][2]))));
            acc2[i][3] = fmaf(av.x, v0.w, fmaf(av.y, v1.w, fmaf(av.z, v2.w, fmaf(av.w, v3.w, acc2[i][3]))));
        }
    }
    float4 bv2 = *(const float4*)&b2[c0];
#pragma unroll
    for (int i = 0; i < 4; ++i) {
        int r = row0 + r0 + i;
        if (r < M) {
            __half2 p0 = __floats2half2_rn(acc2[i][0] + bv2.x, acc2[i][1] + bv2.y);
            __half2 p1 = __floats2half2_rn(acc2[i][2] + bv2.z, acc2[i][3] + bv2.w);
            uint2 pk;
            pk.x = *(unsigned int*)&p0;
            pk.y = *(unsigned int*)&p1;
            *(uint2*)&Zh[(size_t)r * DIM + c0] = pk;
        }
    }
}

// ---------------- last GEMM: relu(X@W+b) -> column sums only
__global__ __launch_bounds__(256) void k_gemm_last(const float* __restrict__ A,
                                                   const float* __restrict__ W,
                                                   const float* __restrict__ bias,
                                                   int M, float* __restrict__ colsum) {
    __shared__ float As[64][68];
    __shared__ float Bs[64][64];
    int t = threadIdx.x;
    int row0 = blockIdx.x * 64;
#pragma unroll
    for (int i = 0; i < 4; ++i) {
        int idx = t + i * 256;
        int r = idx >> 4, c = (idx & 15) << 2;
        float4 val = make_float4(0.f, 0.f, 0.f, 0.f);
        if (row0 + r < M) val = *(const float4*)&A[(size_t)(row0 + r) * DIM + c];
        *(float4*)&As[r][c] = val;
        *(float4*)&Bs[r][c] = *(const float4*)&W[r * DIM + c];
    }
    __syncthreads();
    int r0 = (t >> 4) * 4;
    int c0 = (t & 15) * 4;
    float acc[4][4] = {};
#pragma unroll
    for (int k = 0; k < 64; k += 4) {
        float4 b0 = *(float4*)&Bs[k + 0][c0];
        float4 b1 = *(float4*)&Bs[k + 1][c0];
        float4 b2 = *(float4*)&Bs[k + 2][c0];
        float4 b3 = *(float4*)&Bs[k + 3][c0];
#pragma unroll
        for (int i = 0; i < 4; ++i) {
            float4 av = *(float4*)&As[r0 + i][k];
            acc[i][0] = fmaf(av.x, b0.x, fmaf(av.y, b1.x, fmaf(av.z, b2.x, fmaf(av.w, b3.x, acc[i][0]))));
            acc[i][1] = fmaf(av.x, b0.y, fmaf(av.y, b1.y, fmaf(av.z, b2.y, fmaf(av.w, b3.y, acc[i][1]))));
            acc[i][2] = fmaf(av.x, b0.z, fmaf(av.y, b1.z, fmaf(av.z, b2.z, fmaf(av.w, b3.z, acc[i][2]))));
            acc[i][3] = fmaf(av.x, b0.w, fmaf(av.y, b1.w, fmaf(av.z, b2.w, fmaf(av.w, b3.w, acc[i][3]))));
        }
    }
    float4 bv = *(const float4*)&bias[c0];
    float csum[4] = {0.f, 0.f, 0.f, 0.f};
#pragma unroll
    for (int i = 0; i < 4; ++i) {
        int r = row0 + r0 + i;
        if (r < M) {
            csum[0] += fmaxf(acc[i][0] + bv.x, 0.f);
            csum[1] += fmaxf(acc[i][1] + bv.y, 0.f);
            csum[2] += fmaxf(acc[i][2] + bv.z, 0.f);
            csum[3] += fmaxf(acc[i][3] + bv.w, 0.f);
        }
    }
    float* red = &As[0][0];
    __syncthreads();
    *(float4*)&red[(t >> 4) * 64 + c0] = make_float4(csum[0], csum[1], csum[2], csum[3]);
    __syncthreads();
    if (t < 64) {
        float s = 0.f;
#pragma unroll
        for (int g = 0; g < 16; ++g) s += red[g * 64 + t];
        atomicAdd(&colsum[t], s);
    }
}

// ---------------- aggregation: wave per node, ALWAYS 8-deep gather pipeline.
// Quarter-wave g handles edge 4j+g; se[] zero-padded, rec 0 => weight +0 and a
// broadcast gather of row 0 (L1-cached) — padding is near-free, so every node
// completes its gathers in ceil(quads/8) latency windows (usually 1).
__global__ __launch_bounds__(256) void k_agg(const uint2* __restrict__ Hq,
                                             const float* __restrict__ dis,
                                             const int* __restrict__ row_ptr,
                                             const int* __restrict__ edges,
                                             float* __restrict__ X) {
    __shared__ int se[4][64];
    int w = threadIdx.x >> 6, l = threadIdx.x & 63;
    int node = (blockIdx.x << 2) + w;
    if (node >= NN) return;
    int start = row_ptr[node];
    int num = row_ptr[node + 1] - start;
    int g = l >> 4;           // edge subgroup 0..3
    int p = l & 15;           // feature quad 0..15
    float4 acc = {0.f, 0.f, 0.f, 0.f};
    for (int base = 0; base < num; base += 64) {
        int lim = min(64, num - base);
        se[w][l] = (l < lim) ? edges[start + base + l] : 0;
        __builtin_amdgcn_wave_barrier();
        int quads = (lim + 3) >> 2;          // 1..16
        for (int j = 0; j < quads; j += 8) { // indices 4*(j+q)+g <= 63 always
            int rr[8]; uint2 hh[8];
#pragma unroll
            for (int q = 0; q < 8; ++q) rr[q] = se[w][4 * (j + q) + g];
#pragma unroll
            for (int q = 0; q < 8; ++q) hh[q] = Hq[((rr[q] & 0xFFFF) << 4) + p];
#pragma unroll
            for (int q = 0; q < 8; ++q) {
                float wt = __half2float(__ushort_as_half((ushort)((unsigned)rr[q] >> 16)));
                float2 f0 = __half22float2(*(const __half2*)&hh[q].x);
                float2 f1 = __half22float2(*(const __half2*)&hh[q].y);
                acc.x = fmaf(wt, f0.x, acc.x);
                acc.y = fmaf(wt, f0.y, acc.y);
                acc.z = fmaf(wt, f1.x, acc.z);
                acc.w = fmaf(wt, f1.y, acc.w);
            }
        }
        __builtin_amdgcn_wave_barrier();
    }
    // reduce the 4 edge-subgroup partials
#pragma unroll
    for (int m = 16; m < 64; m <<= 1) {
        acc.x += __shfl_xor(acc.x, m, 64);
        acc.y += __shfl_xor(acc.y, m, 64);
        acc.z += __shfl_xor(acc.z, m, 64);
        acc.w += __shfl_xor(acc.w, m, 64);
    }
    if (g == 0) {
        uint2 sv = Hq[(node << 4) + p];
        float2 s0 = __half22float2(*(const __half2*)&sv.x);
        float2 s1 = __half22float2(*(const __half2*)&sv.y);
        float dv = dis[node];
        float4 o;
        o.x = fmaf(dv, acc.x, s0.x);
        o.y = fmaf(dv, acc.y, s0.y);
        o.z = fmaf(dv, acc.z, s1.x);
        o.w = fmaf(dv, acc.w, s1.y);
        *(float4*)&X[((size_t)node << 6) + (p << 2)] = o;
    }
}

// ---------------- readout
__global__ void k_out(const float* __restrict__ colsum, const float* __restrict__ out_w,
                      const float* __restrict__ out_b, float* __restrict__ out) {
    int f = threadIdx.x;
    float v = colsum[f] * (1.0f / (float)NN) * out_w[f];
    for (int off = 32; off; off >>= 1) v += __shfl_down(v, off, 64);
    if (f == 0) out[0] = v + out_b[0];
}

extern "C" void kernel_launch(void* const* d_in, const int* in_sizes, int n_in,
                              void* d_out, int out_size, void* d_ws, size_t ws_size,
                              hipStream_t stream) {
    const float* H  = (const float*)d_in[0];
    const int*   ei = (const int*)d_in[1];
    const float* enc_w[3] = { (const float*)d_in[3], (const float*)d_in[7],  (const float*)d_in[11] };
    const float* enc_b[3] = { (const float*)d_in[4], (const float*)d_in[8],  (const float*)d_in[12] };
    const float* upd_w[3] = { (const float*)d_in[5], (const float*)d_in[9],  (const float*)d_in[13] };
    const float* upd_b[3] = { (const float*)d_in[6], (const float*)d_in[10], (const float*)d_in[14] };
    const float* out_w = (const float*)d_in[15];
    const float* out_b = (const float*)d_in[16];
    float* out = (float*)d_out;

    size_t off = 0;
    auto carve = [&](size_t bytes) {
        void* p = (char*)d_ws + off;
        off = (off + bytes + 255) & ~(size_t)255;
        return p;
    };
    int*    lpart_u = (int*)carve((size_t)SLICES * (NB + 1) * 4);
    int*    lpart_v = (int*)carve((size_t)SLICES * (NB + 1) * 4);
    int*    tot     = (int*)carve((size_t)NB * 4);
    int*    base_v  = (int*)carve((size_t)(NB + 1) * 4);
    float*  dis     = (float*)carve((size_t)NN * 4);
    ushort* usort   = (ushort*)carve((size_t)SLICES * ES * 2);
    int*    ebuf    = (int*)carve((size_t)SLICES * ES * 4);
    int*    edges   = (int*)carve((size_t)NE * 4);
    int*    row_ptr = (int*)carve((size_t)(NN + 65) * 4);
    __half* Ch      = (__half*)carve((size_t)NN * DIM * 2);
    float*  X       = (float*)carve((size_t)NN * DIM * 4);
    float*  colsum  = (float*)carve(64 * 4);

    const int AB = (NN + 3) / 4;     // 12500
    const uint2* Hq = (const uint2*)Ch;

    // front: slice-sort (256 blocks) overlapped with enc-GEMM-0 (782 blocks)
    k_front<<<SLICES + GB, 256, FRONT_LDS, stream>>>(ei, usort, ebuf, lpart_u, lpart_v,
                                                     H, enc_w[0], enc_b[0], Ch);
    k_mid<<<2 * BB, 256, 0, stream>>>(usort, lpart_u, lpart_v, dis, tot);
    k_scanB<<<1, 256, 0, stream>>>(tot, base_v, colsum);
    k_vsort<<<BB, 256, 0, stream>>>(ebuf, lpart_v, base_v, dis, edges, row_ptr);

    k_agg<<<AB, 256, 0, stream>>>(Hq, dis, row_ptr, edges, X);
    k_gemm2<<<GB, 256, 0, stream>>>(X, upd_w[0], upd_b[0], enc_w[1], enc_b[1], Ch, NN);
    k_agg<<<AB, 256, 0, stream>>>(Hq, dis, row_ptr, edges, X);
    k_gemm2<<<GB, 256, 0, stream>>>(X, upd_w[1], upd_b[1], enc_w[2], enc_b[2], Ch, NN);
    k_agg<<<AB, 256, 0, stream>>>(Hq, dis, row_ptr, edges, X);
    k_gemm_last<<<GB, 256, 0, stream>>>(X, upd_w[2], upd_b[2], NN, colsum);

    k_out<<<1, 64, 0, stream>>>(colsum, out_w, out_b, out);
}